// Round 5
// baseline (624.197 us; speedup 1.0000x reference)
//
#include <hip/hip_runtime.h>
#include <hip/hip_bf16.h>
#include <stdint.h>

typedef __attribute__((ext_vector_type(4))) float f32x4;
typedef __attribute__((ext_vector_type(8))) short short8;

#define B_   64
#define S_   512
#define H_   1024
#define E_   512
#define V_   32000
#define M_   2048            // D*H
#define BS_  32768           // B*S
#define XIN_ 2560            // M_+E_
#define G3_  3072

__device__ __forceinline__ unsigned short f2bf(float f) {
  union { float f; unsigned u; } x; x.f = f;
  unsigned r = x.u + 0x7fffu + ((x.u >> 16) & 1u);
  return (unsigned short)(r >> 16);
}

__device__ __forceinline__ float bf2f(unsigned short u) {
  union { unsigned u; float f; } x; x.u = (unsigned)u << 16; return x.f;
}

__device__ __forceinline__ void async16(const void* g, void* l) {
  __builtin_amdgcn_global_load_lds((const __attribute__((address_space(1))) unsigned*)g,
                                   (__attribute__((address_space(3))) unsigned*)l,
                                   16, 0, 0);
}

// ------- merged converter: enc->bf16 (16B stores), lin2_w->bf16, emb gather --
__global__ __launch_bounds__(256) void k_conv(const float* __restrict__ enc,
                                              unsigned short* __restrict__ ebf,
                                              const float* __restrict__ lin2w,
                                              unsigned short* __restrict__ bw,
                                              const int* __restrict__ word,
                                              const float* __restrict__ emb,
                                              float* __restrict__ wv) {
  const size_t NENC8 = (size_t)BS_ * M_ / 8;   // 8,388,608
  const size_t NW8   = (size_t)H_ * M_ / 8;    // 262,144
  const size_t NWV4  = (size_t)B_ * E_ / 4;    // 8,192
  const size_t total = NENC8 + NW8 + NWV4;
  for (size_t idx = (size_t)blockIdx.x * 256 + threadIdx.x; idx < total;
       idx += (size_t)gridDim.x * 256) {
    if (idx < NENC8) {
      f32x4 a = *(const f32x4*)(enc + idx * 8);
      f32x4 b = *(const f32x4*)(enc + idx * 8 + 4);
      short8 o = { (short)f2bf(a.x), (short)f2bf(a.y), (short)f2bf(a.z), (short)f2bf(a.w),
                   (short)f2bf(b.x), (short)f2bf(b.y), (short)f2bf(b.z), (short)f2bf(b.w) };
      *(short8*)(ebf + idx * 8) = o;
    } else if (idx < NENC8 + NW8) {
      size_t i = idx - NENC8;
      f32x4 a = *(const f32x4*)(lin2w + i * 8);
      f32x4 b = *(const f32x4*)(lin2w + i * 8 + 4);
      short8 o = { (short)f2bf(a.x), (short)f2bf(a.y), (short)f2bf(a.z), (short)f2bf(a.w),
                   (short)f2bf(b.x), (short)f2bf(b.y), (short)f2bf(b.z), (short)f2bf(b.w) };
      *(short8*)(bw + i * 8) = o;
    } else {
      size_t i = idx - NENC8 - NW8;     // < 8192
      int i0 = (int)i * 4;
      int b = i0 >> 9, c = i0 & 511;
      f32x4 v = *(const f32x4*)(emb + (size_t)word[b] * E_ + c);
      *(f32x4*)(wv + i0) = v;
    }
  }
}

// ---------------- h_x = hidden @ lin1_w.T + b1 + b2 (LDS-tiled 64x64) -------
__global__ __launch_bounds__(256) void k_hx(const float* __restrict__ hidden,
                                            const float* __restrict__ w1,
                                            const float* __restrict__ b1,
                                            const float* __restrict__ b2,
                                            float* __restrict__ hx) {
  __shared__ float hs[64][36];
  __shared__ float Ws[64][36];
  const int t = threadIdx.x;
  const int hbase = blockIdx.x * 64;     // 16 blocks
  const int hb = t & 15, bb = t >> 4;
  const int srow = t >> 2, sc0 = (t & 3) * 8;
  float acc[4][4] = {};
  for (int kc = 0; kc < H_; kc += 32) {
    *(f32x4*)&hs[srow][sc0]     = *(const f32x4*)(hidden + (size_t)srow * H_ + kc + sc0);
    *(f32x4*)&hs[srow][sc0 + 4] = *(const f32x4*)(hidden + (size_t)srow * H_ + kc + sc0 + 4);
    *(f32x4*)&Ws[srow][sc0]     = *(const f32x4*)(w1 + (size_t)(hbase + srow) * H_ + kc + sc0);
    *(f32x4*)&Ws[srow][sc0 + 4] = *(const f32x4*)(w1 + (size_t)(hbase + srow) * H_ + kc + sc0 + 4);
    __syncthreads();
#pragma unroll
    for (int kk = 0; kk < 32; ++kk) {
      float a[4], w4[4];
#pragma unroll
      for (int i = 0; i < 4; ++i) a[i] = hs[bb * 4 + i][kk];
#pragma unroll
      for (int j = 0; j < 4; ++j) w4[j] = Ws[hb + 16 * j][kk];
#pragma unroll
      for (int i = 0; i < 4; ++i)
#pragma unroll
        for (int j = 0; j < 4; ++j) acc[i][j] += a[i] * w4[j];
    }
    __syncthreads();
  }
#pragma unroll
  for (int i = 0; i < 4; ++i)
#pragma unroll
    for (int j = 0; j < 4; ++j) {
      int h = hbase + hb + 16 * j;
      hx[(size_t)(bb * 4 + i) * H_ + h] = acc[i][j] + b1[h] + b2[h];
    }
}

// ---------------- attention GEMM: 128x128 tile, BK=64, conflict-free LDS ----
// LDS layout: [ks 8][row 128][8 bf16] (byte = ks*2048 + row*16) -> consecutive
// lanes read consecutive rows => conflict-free ds_read_b128 (k_attn8-verified).
__global__ __launch_bounds__(256) void k_attn_bf(const unsigned short* __restrict__ encbf,
                                                 const unsigned short* __restrict__ bw,
                                                 const float* __restrict__ hx,
                                                 const float* __restrict__ vw,
                                                 float* __restrict__ epart) {
  __shared__ unsigned short As[8192];   // 16 KB
  __shared__ unsigned short Bs[8192];   // 16 KB
  const int bid = blockIdx.x;              // 2048
  const int xcd = bid & 7, idx = bid >> 3;
  const int bm = xcd * 32 + (idx >> 3);
  const int bn = idx & 7;
  const int t = threadIdx.x;
  const int l = t & 63, w = t >> 6;
  const int wr = w >> 1, wc = w & 1;
  const int l15 = l & 15, l4 = l >> 4;

  f32x4 acc[4][4] = {};

  const unsigned short* Ag = encbf + (size_t)(bm * 128) * M_;
  const unsigned short* Bg = bw + (size_t)(bn * 128) * M_;

  const int srow = t & 127;        // stage row
  const int sj = t >> 7;           // k-slot parity

  for (int kt = 0; kt < 32; ++kt) {
    const int k0 = kt * 64;
#pragma unroll
    for (int j = 0; j < 4; ++j) {
      async16(Ag + (size_t)srow * M_ + k0 + (j * 2 + sj) * 8, (char*)As + j * 4096 + t * 16);
      async16(Bg + (size_t)srow * M_ + k0 + (j * 2 + sj) * 8, (char*)Bs + j * 4096 + t * 16);
    }
    __syncthreads();
    short8 af[4][2], bf[4][2];
#pragma unroll
    for (int m = 0; m < 4; ++m)
#pragma unroll
      for (int kh = 0; kh < 2; ++kh)
        af[m][kh] = *(const short8*)((char*)As + (kh * 4 + l4) * 2048 + (wr * 64 + m * 16 + l15) * 16);
#pragma unroll
    for (int n = 0; n < 4; ++n)
#pragma unroll
      for (int kh = 0; kh < 2; ++kh)
        bf[n][kh] = *(const short8*)((char*)Bs + (kh * 4 + l4) * 2048 + (wc * 64 + n * 16 + l15) * 16);
#pragma unroll
    for (int m = 0; m < 4; ++m)
#pragma unroll
      for (int n = 0; n < 4; ++n) {
        acc[m][n] = __builtin_amdgcn_mfma_f32_16x16x32_bf16(af[m][0], bf[n][0], acc[m][n], 0, 0, 0);
        acc[m][n] = __builtin_amdgcn_mfma_f32_16x16x32_bf16(af[m][1], bf[n][1], acc[m][n], 0, 0, 0);
      }
    __syncthreads();
  }

  const int colbase = bn * 128 + wc * 64;
#pragma unroll
  for (int m = 0; m < 4; ++m) {
#pragma unroll
    for (int j = 0; j < 4; ++j) {
      int rloc = wr * 64 + m * 16 + l4 * 4 + j;
      int rg = bm * 128 + rloc;
      int b = rg >> 9;
      float sum = 0.f;
#pragma unroll
      for (int n = 0; n < 4; ++n) {
        int h = colbase + n * 16 + l15;
        sum += vw[h] * tanhf(hx[b * H_ + h] + acc[m][n][j]);
      }
      sum += __shfl_xor(sum, 1);
      sum += __shfl_xor(sum, 2);
      sum += __shfl_xor(sum, 4);
      sum += __shfl_xor(sum, 8);
      if (l15 == 0) epart[(size_t)(bn * 2 + wc) * BS_ + rg] = sum;
    }
  }
}

// ---------------- attention GEMM (slow fallback: fused f32 A conversion) ----
__global__ __launch_bounds__(256) void k_attn(const float* __restrict__ enc,
                                              const unsigned short* __restrict__ bw,
                                              const float* __restrict__ hx,
                                              const float* __restrict__ vw,
                                              float* __restrict__ epart) {
  __shared__ unsigned short As[128 * 32];
  __shared__ unsigned short Bs[128 * 32];
  const int bid = blockIdx.x;
  const int bm = bid & 255, bn = bid >> 8;
  const int t = threadIdx.x;
  const int l = t & 63, w = t >> 6;
  const int wr = w >> 1, wc = w & 1;
  const int l15 = l & 15, l4 = l >> 4;

  f32x4 acc[4][4] = {};

  const float* Ag = enc + (size_t)(bm * 128) * M_;
  const unsigned short* Bg = bw + (size_t)(bn * 128) * M_;

  const int ar = t >> 3;
  const int ac = (t & 7) * 4;
  const int br = t >> 2;
  const int bc = (t & 3) * 8;

  for (int kt = 0; kt < 64; ++kt) {
    const int k0 = kt * 32;
    async16(Bg + (size_t)br * M_ + k0 + bc, (char*)Bs + (size_t)t * 16);
    async16(Bg + (size_t)(br + 64) * M_ + k0 + bc, (char*)Bs + 4096 + (size_t)t * 16);
#pragma unroll
    for (int j = 0; j < 4; ++j) {
      f32x4 v = *(const f32x4*)(Ag + (size_t)(ar + j * 32) * M_ + k0 + ac);
      ushort4 o = { f2bf(v.x), f2bf(v.y), f2bf(v.z), f2bf(v.w) };
      *(ushort4*)(As + (ar + j * 32) * 32 + ac) = o;
    }
    __syncthreads();
    short8 af[4], bf[4];
#pragma unroll
    for (int m = 0; m < 4; ++m)
      af[m] = *(const short8*)(As + (wr * 64 + m * 16 + l15) * 32 + l4 * 8);
#pragma unroll
    for (int n = 0; n < 4; ++n)
      bf[n] = *(const short8*)(Bs + (wc * 64 + n * 16 + l15) * 32 + l4 * 8);
#pragma unroll
    for (int m = 0; m < 4; ++m)
#pragma unroll
      for (int n = 0; n < 4; ++n)
        acc[m][n] = __builtin_amdgcn_mfma_f32_16x16x32_bf16(af[m], bf[n], acc[m][n], 0, 0, 0);
    __syncthreads();
  }

  const int colbase = bn * 128 + wc * 64;
#pragma unroll
  for (int m = 0; m < 4; ++m) {
#pragma unroll
    for (int j = 0; j < 4; ++j) {
      int rloc = wr * 64 + m * 16 + l4 * 4 + j;
      int rg = bm * 128 + rloc;
      int b = rg >> 9;
      float sum = 0.f;
#pragma unroll
      for (int n = 0; n < 4; ++n) {
        int h = colbase + n * 16 + l15;
        sum += vw[h] * tanhf(hx[b * H_ + h] + acc[m][n][j]);
      }
      sum += __shfl_xor(sum, 1);
      sum += __shfl_xor(sum, 2);
      sum += __shfl_xor(sum, 4);
      sum += __shfl_xor(sum, 8);
      if (l15 == 0) epart[(size_t)(bn * 2 + wc) * BS_ + rg] = sum;
    }
  }
}

// ---------------- softmax over S per batch row (reduces 16 e-partials) ------
__global__ __launch_bounds__(256) void k_softmax(const float* __restrict__ epart,
                                                 float* __restrict__ score) {
  int b = blockIdx.x, t = threadIdx.x;
  float v0 = 0.f, v1 = 0.f;
#pragma unroll
  for (int p = 0; p < 16; ++p) {
    v0 += epart[(size_t)p * BS_ + b * S_ + t];
    v1 += epart[(size_t)p * BS_ + b * S_ + 256 + t];
  }
  int w = t >> 6, l = t & 63;
  float m = fmaxf(v0, v1);
#pragma unroll
  for (int off = 32; off; off >>= 1) m = fmaxf(m, __shfl_xor(m, off));
  __shared__ float sm[4];
  __shared__ float ssum[4];
  if (l == 0) sm[w] = m;
  __syncthreads();
  float M = fmaxf(fmaxf(sm[0], sm[1]), fmaxf(sm[2], sm[3]));
  float p0 = expf(v0 - M), p1 = expf(v1 - M);
  float s = p0 + p1;
#pragma unroll
  for (int off = 32; off; off >>= 1) s += __shfl_xor(s, off);
  if (l == 0) ssum[w] = s;
  __syncthreads();
  float inv = 1.f / (ssum[0] + ssum[1] + ssum[2] + ssum[3]);
  score[b * S_ + t] = p0 * inv;
  score[b * S_ + 256 + t] = p1 * inv;
}

// ---------------- context partials (bf16 enc read) ----------------
__global__ __launch_bounds__(256) void k_ctxb(const unsigned short* __restrict__ encbf,
                                              const float* __restrict__ score,
                                              float* __restrict__ cpart) {
  int blk = blockIdx.x;            // 512 = b(64) x sc(8)
  int b = blk >> 3, sc = blk & 7;
  int t = threadIdx.x;
  int m = t * 8;
  f32x4 acc0 = {0.f, 0.f, 0.f, 0.f}, acc1 = {0.f, 0.f, 0.f, 0.f};
  const unsigned short* ep = encbf + (size_t)(b * S_ + sc * 64) * M_ + m;
  const float* sp = score + b * S_ + sc * 64;
#pragma unroll 4
  for (int s8 = 0; s8 < 64; ++s8) {
    float sv = sp[s8];
    short8 v = *(const short8*)(ep + (size_t)s8 * M_);
    acc0.x += bf2f((unsigned short)v[0]) * sv;
    acc0.y += bf2f((unsigned short)v[1]) * sv;
    acc0.z += bf2f((unsigned short)v[2]) * sv;
    acc0.w += bf2f((unsigned short)v[3]) * sv;
    acc1.x += bf2f((unsigned short)v[4]) * sv;
    acc1.y += bf2f((unsigned short)v[5]) * sv;
    acc1.z += bf2f((unsigned short)v[6]) * sv;
    acc1.w += bf2f((unsigned short)v[7]) * sv;
  }
  float* dst = cpart + (size_t)sc * (B_ * M_) + b * M_ + m;
  *(f32x4*)dst = acc0;
  *(f32x4*)(dst + 4) = acc1;
}

// ---------------- context partials (f32 fallback) ----------------
__global__ __launch_bounds__(256) void k_ctx(const float* __restrict__ enc,
                                             const float* __restrict__ score,
                                             float* __restrict__ cpart) {
  int blk = blockIdx.x;
  int b = blk >> 4, mc = (blk >> 3) & 1, sc = blk & 7;
  int t = threadIdx.x;
  int m = mc * 1024 + t * 4;
  f32x4 acc = {0.f, 0.f, 0.f, 0.f};
  const float* ep = enc + (size_t)b * S_ * M_ + m;
  const float* sp = score + b * S_ + sc * 64;
#pragma unroll 4
  for (int s8 = 0; s8 < 64; ++s8) {
    float sv = sp[s8];
    f32x4 v = *(const f32x4*)(ep + (size_t)(sc * 64 + s8) * M_);
    acc += v * sv;
  }
  *(f32x4*)(cpart + (size_t)sc * (B_ * M_) + b * M_ + m) = acc;
}

__global__ void k_ctxred(const float* __restrict__ cpart, float* __restrict__ ctx) {
  int i0 = (blockIdx.x * 256 + threadIdx.x) * 4;
  f32x4 a = {0.f, 0.f, 0.f, 0.f};
#pragma unroll
  for (int p = 0; p < 8; ++p) a += *(const f32x4*)(cpart + (size_t)p * (B_ * M_) + i0);
  *(f32x4*)(ctx + i0) = a;
}

// ---------------- GRU GEMMs: 64x64 tile, 4x4/thread, K-split x2 -------------
// blocks 0..95: gi (colt = b%48, half = b/48); 96..191: gh likewise
__global__ __launch_bounds__(256) void k_grugemm(const float* __restrict__ ctx,
                                                 const float* __restrict__ wv,
                                                 const float* __restrict__ hidden,
                                                 const float* __restrict__ Wih,
                                                 const float* __restrict__ bih,
                                                 const float* __restrict__ Whh,
                                                 const float* __restrict__ bhh,
                                                 float* __restrict__ gi0,
                                                 float* __restrict__ gi1,
                                                 float* __restrict__ gh0,
                                                 float* __restrict__ gh1) {
  __shared__ float xs[64][36];
  __shared__ float Ws[64][36];
  const int t = threadIdx.x;
  const int blk = blockIdx.x;
  const bool ghh = blk >= 96;
  const int sub = ghh ? blk - 96 : blk;
  const int colt = sub % 48, half = sub / 48;
  const int gbase = colt * 64;
  const int K = ghh ? H_ : XIN_;
  const int klo = ghh ? (half ? 512 : 0) : (half ? 1280 : 0);
  const int khi = ghh ? (half ? 1024 : 512) : (half ? 2560 : 1280);
  const float* Wp = ghh ? Whh : Wih;
  const int vb = t & 15, bb = t >> 4;
  const int srow = t >> 2, sc0 = (t & 3) * 8;
  float acc[4][4] = {};
  for (int kc = klo; kc < khi; kc += 32) {
    f32x4 xa, xb;
    if (ghh) {
      xa = *(const f32x4*)(hidden + (size_t)srow * H_ + kc + sc0);
      xb = *(const f32x4*)(hidden + (size_t)srow * H_ + kc + sc0 + 4);
    } else if (kc + sc0 < M_) {
      xa = *(const f32x4*)(ctx + (size_t)srow * M_ + kc + sc0);
      xb = *(const f32x4*)(ctx + (size_t)srow * M_ + kc + sc0 + 4);
    } else {
      xa = *(const f32x4*)(wv + (size_t)srow * E_ + kc + sc0 - M_);
      xb = *(const f32x4*)(wv + (size_t)srow * E_ + kc + sc0 - M_ + 4);
    }
    *(f32x4*)&xs[srow][sc0] = xa;
    *(f32x4*)&xs[srow][sc0 + 4] = xb;
    *(f32x4*)&Ws[srow][sc0]     = *(const f32x4*)(Wp + (size_t)(gbase + srow) * K + kc + sc0);
    *(f32x4*)&Ws[srow][sc0 + 4] = *(const f32x4*)(Wp + (size_t)(gbase + srow) * K + kc + sc0 + 4);
    __syncthreads();
#pragma unroll
    for (int kk = 0; kk < 32; ++kk) {
      float a[4], w4[4];
#pragma unroll
      for (int i = 0; i < 4; ++i) a[i] = xs[bb * 4 + i][kk];
#pragma unroll
      for (int j = 0; j < 4; ++j) w4[j] = Ws[vb + 16 * j][kk];
#pragma unroll
      for (int i = 0; i < 4; ++i)
#pragma unroll
        for (int j = 0; j < 4; ++j) acc[i][j] += a[i] * w4[j];
    }
    __syncthreads();
  }
  float* dst = ghh ? (half ? gh1 : gh0) : (half ? gi1 : gi0);
  const float* bias = ghh ? bhh : bih;
#pragma unroll
  for (int i = 0; i < 4; ++i)
#pragma unroll
    for (int j = 0; j < 4; ++j) {
      int g = gbase + vb + 16 * j;
      float v = acc[i][j] + (half ? 0.f : bias[g]);
      dst[(size_t)(bb * 4 + i) * G3_ + g] = v;
    }
}

// ---------------- GRU gates -> new_hidden (f32 + bf16 copy) ----------------
__global__ void k_gate(const float* __restrict__ gi0, const float* __restrict__ gi1,
                       const float* __restrict__ gh0, const float* __restrict__ gh1,
                       const float* __restrict__ hidden, float* __restrict__ newh,
                       unsigned short* __restrict__ newhbf) {
  int o = blockIdx.x * 256 + threadIdx.x;
  int b = o >> 10, h = o & 1023;
  size_t base = (size_t)b * G3_;
  float ir = gi0[base + h] + gi1[base + h];
  float iz = gi0[base + 1024 + h] + gi1[base + 1024 + h];
  float in = gi0[base + 2048 + h] + gi1[base + 2048 + h];
  float hr = gh0[base + h] + gh1[base + h];
  float hz = gh0[base + 1024 + h] + gh1[base + 1024 + h];
  float hn = gh0[base + 2048 + h] + gh1[base + 2048 + h];
  float r = 1.f / (1.f + expf(-(ir + hr)));
  float z = 1.f / (1.f + expf(-(iz + hz)));
  float n = tanhf(in + r * hn);
  float nh = (1.f - z) * n + z * hidden[o];
  newh[o] = nh;
  newhbf[o] = f2bf(nh);
}

// ---------------- output projection: bf16 MFMA, 64x128 tile ----------------
__global__ __launch_bounds__(256) void k_outproj_mfma(const unsigned short* __restrict__ newhbf,
                                                      const float* __restrict__ ow,
                                                      const float* __restrict__ ob,
                                                      float* __restrict__ pred) {
  __shared__ unsigned short As[2048];   // 4 KB
  __shared__ unsigned short Bs[4096];   // 8 KB
  const int t = threadIdx.x;
  const int w = t >> 6, l = t & 63;
  const int l15 = l & 15, l4 = l >> 4;
  const int vbase = blockIdx.x * 128;   // 250 blocks

  const unsigned short* aSrc = newhbf + (size_t)(t & 63) * H_ + (t >> 6) * 8;
  const int br = t >> 1, bh = t & 1;
  const float* bSrc = ow + (size_t)(vbase + br) * H_ + bh * 16;

  f32x4 acc[4][2] = {};

  for (int kc = 0; kc < H_; kc += 32) {
    async16(aSrc + kc, (char*)As + (size_t)t * 16);
    f32x4 v0 = *(const f32x4*)(bSrc + kc);
    f32x4 v1 = *(const f32x4*)(bSrc + kc + 4);
    f32x4 v2 = *(const f32x4*)(bSrc + kc + 8);
    f32x4 v3 = *(const f32x4*)(bSrc + kc + 12);
    ushort4 p0 = { f2bf(v0.x), f2bf(v0.y), f2bf(v0.z), f2bf(v0.w) };
    ushort4 p1 = { f2bf(v1.x), f2bf(v1.y), f2bf(v1.z), f2bf(v1.w) };
    ushort4 p2 = { f2bf(v2.x), f2bf(v2.y), f2bf(v2.z), f2bf(v2.w) };
    ushort4 p3 = { f2bf(v3.x), f2bf(v3.y), f2bf(v3.z), f2bf(v3.w) };
    const int kg0 = bh * 2;
    *(ushort4*)(Bs + kg0 * 1024 + br * 8)       = p0;
    *(ushort4*)(Bs + kg0 * 1024 + br * 8 + 4)   = p1;
    *(ushort4*)(Bs + (kg0 + 1) * 1024 + br * 8)     = p2;
    *(ushort4*)(Bs + (kg0 + 1) * 1024 + br * 8 + 4) = p3;
    __syncthreads();
    short8 af[4], bf[2];
#pragma unroll
    for (int rf = 0; rf < 4; ++rf)
      af[rf] = *(const short8*)(As + l4 * 512 + (rf * 16 + l15) * 8);
#pragma unroll
    for (int cf = 0; cf < 2; ++cf)
      bf[cf] = *(const short8*)(Bs + l4 * 1024 + (w * 32 + cf * 16 + l15) * 8);
#pragma unroll
    for (int rf = 0; rf < 4; ++rf)
#pragma unroll
      for (int cf = 0; cf < 2; ++cf)
        acc[rf][cf] = __builtin_amdgcn_mfma_f32_16x16x32_bf16(af[rf], bf[cf], acc[rf][cf], 0, 0, 0);
    __syncthreads();
  }

#pragma unroll
  for (int cf = 0; cf < 2; ++cf) {
    int col = vbase + w * 32 + cf * 16 + l15;
    float bias = ob[col];
#pragma unroll
    for (int rf = 0; rf < 4; ++rf)
#pragma unroll
      for (int j = 0; j < 4; ++j) {
        int row = rf * 16 + l4 * 4 + j;
        pred[(size_t)row * V_ + col] = acc[rf][cf][j] + bias;
      }
  }
}

extern "C" void kernel_launch(void* const* d_in, const int* in_sizes, int n_in,
                              void* d_out, int out_size, void* d_ws, size_t ws_size,
                              hipStream_t stream) {
  const int*   word   = (const int*)d_in[0];
  const float* hidden = (const float*)d_in[1];
  const float* enc    = (const float*)d_in[2];
  const float* emb    = (const float*)d_in[5];
  const float* lin1w  = (const float*)d_in[6];
  const float* lin1b  = (const float*)d_in[7];
  const float* lin2w  = (const float*)d_in[8];
  const float* lin2b  = (const float*)d_in[9];
  const float* vw     = (const float*)d_in[10];
  const float* Wih    = (const float*)d_in[12];
  const float* bih    = (const float*)d_in[13];
  const float* Whh    = (const float*)d_in[14];
  const float* bhh    = (const float*)d_in[15];
  const float* ow     = (const float*)d_in[16];
  const float* ob     = (const float*)d_in[17];

  float* out   = (float*)d_out;
  float* pred  = out;                   // [64][32000]
  float* newh  = out + 2048000;         // [64][1024]
  float* score = out + 2113536;         // [64][512]

  const size_t ENCBF = 134217728;       // 32768*2048*2
  const bool fast = ws_size >= ENCBF + 13107200;
  char* ws = (char*)d_ws;
  unsigned short* encbf = (unsigned short*)ws;      // fast path only
  size_t base = fast ? ENCBF : 0;
  unsigned short* bw = (unsigned short*)(ws + base);        // 4,194,304
  float* hx    = (float*)(ws + base + 4194304);             // 262,144
  float* wvbuf = (float*)(ws + base + 4456448);             // 131,072
  float* epart = (float*)(ws + base + 4587520);             // 2,097,152
  float* cpart = (float*)(ws + base + 6684672);             // 4,194,304
  float* ctx   = (float*)(ws + base + 10878976);            // 524,288
  float* gi0   = (float*)(ws + base + 11403264);            // 786,432
  float* gh0   = (float*)(ws + base + 12189696);            // 786,432
  unsigned short* nhbf = (unsigned short*)(ws + base + 12976128);  // 131,072
  // gi1/gh1 reuse the dead epart region (epart consumed by k_softmax before
  // k_grugemm runs; stream-serialized)
  float* gi1   = epart;                                     // 786,432
  float* gh1   = epart + 196608;                            // 786,432

  k_hx<<<16, 256, 0, stream>>>(hidden, lin1w, lin1b, lin2b, hx);
  if (fast) {
    k_conv<<<4096, 256, 0, stream>>>(enc, encbf, lin2w, bw, word, emb, wvbuf);
    k_attn_bf<<<2048, 256, 0, stream>>>(encbf, bw, hx, vw, epart);
    k_softmax<<<64, 256, 0, stream>>>(epart, score);
    k_ctxb<<<512, 256, 0, stream>>>(encbf, score, cpart);
  } else {
    k_conv<<<4096, 256, 0, stream>>>(enc, encbf, lin2w, bw, word, emb, wvbuf); // enc part unused
    k_attn<<<2048, 256, 0, stream>>>(enc, bw, hx, vw, epart);
    k_softmax<<<64, 256, 0, stream>>>(epart, score);
    k_ctx<<<1024, 256, 0, stream>>>(enc, score, cpart);
  }
  k_ctxred<<<128, 256, 0, stream>>>(cpart, ctx);
  k_grugemm<<<192, 256, 0, stream>>>(ctx, wvbuf, hidden, Wih, bih, Whh, bhh, gi0, gi1, gh0, gh1);
  k_gate<<<256, 256, 0, stream>>>(gi0, gi1, gh0, gh1, hidden, newh, nhbf);
  k_outproj_mfma<<<250, 256, 0, stream>>>(nhbf, ow, ob, pred);
}

// Round 6
// 511.056 us; speedup vs baseline: 1.2214x; 1.2214x over previous
//
#include <hip/hip_runtime.h>
#include <hip/hip_bf16.h>
#include <stdint.h>

typedef __attribute__((ext_vector_type(4))) float f32x4;
typedef __attribute__((ext_vector_type(8))) short short8;

#define B_   64
#define S_   512
#define H_   1024
#define E_   512
#define V_   32000
#define M_   2048            // D*H
#define BS_  32768           // B*S
#define XIN_ 2560            // M_+E_
#define G3_  3072

__device__ __forceinline__ unsigned short f2bf(float f) {
  union { float f; unsigned u; } x; x.f = f;
  unsigned r = x.u + 0x7fffu + ((x.u >> 16) & 1u);
  return (unsigned short)(r >> 16);
}

__device__ __forceinline__ float bf2f(unsigned short u) {
  union { unsigned u; float f; } x; x.u = (unsigned)u << 16; return x.f;
}

__device__ __forceinline__ void async16(const void* g, void* l) {
  __builtin_amdgcn_global_load_lds((const __attribute__((address_space(1))) unsigned*)g,
                                   (__attribute__((address_space(3))) unsigned*)l,
                                   16, 0, 0);
}

// ------- merged converter: enc->bf16 (16B stores), lin2_w->bf16, emb gather --
__global__ __launch_bounds__(256) void k_conv(const float* __restrict__ enc,
                                              unsigned short* __restrict__ ebf,
                                              const float* __restrict__ lin2w,
                                              unsigned short* __restrict__ bw,
                                              const int* __restrict__ word,
                                              const float* __restrict__ emb,
                                              float* __restrict__ wv) {
  const size_t NENC8 = (size_t)BS_ * M_ / 8;   // 8,388,608
  const size_t NW8   = (size_t)H_ * M_ / 8;    // 262,144
  const size_t NWV4  = (size_t)B_ * E_ / 4;    // 8,192
  const size_t total = NENC8 + NW8 + NWV4;
  for (size_t idx = (size_t)blockIdx.x * 256 + threadIdx.x; idx < total;
       idx += (size_t)gridDim.x * 256) {
    if (idx < NENC8) {
      f32x4 a = *(const f32x4*)(enc + idx * 8);
      f32x4 b = *(const f32x4*)(enc + idx * 8 + 4);
      short8 o = { (short)f2bf(a.x), (short)f2bf(a.y), (short)f2bf(a.z), (short)f2bf(a.w),
                   (short)f2bf(b.x), (short)f2bf(b.y), (short)f2bf(b.z), (short)f2bf(b.w) };
      *(short8*)(ebf + idx * 8) = o;
    } else if (idx < NENC8 + NW8) {
      size_t i = idx - NENC8;
      f32x4 a = *(const f32x4*)(lin2w + i * 8);
      f32x4 b = *(const f32x4*)(lin2w + i * 8 + 4);
      short8 o = { (short)f2bf(a.x), (short)f2bf(a.y), (short)f2bf(a.z), (short)f2bf(a.w),
                   (short)f2bf(b.x), (short)f2bf(b.y), (short)f2bf(b.z), (short)f2bf(b.w) };
      *(short8*)(bw + i * 8) = o;
    } else {
      size_t i = idx - NENC8 - NW8;     // < 8192
      int i0 = (int)i * 4;
      int b = i0 >> 9, c = i0 & 511;
      f32x4 v = *(const f32x4*)(emb + (size_t)word[b] * E_ + c);
      *(f32x4*)(wv + i0) = v;
    }
  }
}

// ---------------- h_x = hidden @ lin1_w.T + b1 + b2 (LDS-tiled 64x64) -------
__global__ __launch_bounds__(256) void k_hx(const float* __restrict__ hidden,
                                            const float* __restrict__ w1,
                                            const float* __restrict__ b1,
                                            const float* __restrict__ b2,
                                            float* __restrict__ hx) {
  __shared__ float hs[64][36];
  __shared__ float Ws[64][36];
  const int t = threadIdx.x;
  const int hbase = blockIdx.x * 64;     // 16 blocks
  const int hb = t & 15, bb = t >> 4;
  const int srow = t >> 2, sc0 = (t & 3) * 8;
  float acc[4][4] = {};
  for (int kc = 0; kc < H_; kc += 32) {
    *(f32x4*)&hs[srow][sc0]     = *(const f32x4*)(hidden + (size_t)srow * H_ + kc + sc0);
    *(f32x4*)&hs[srow][sc0 + 4] = *(const f32x4*)(hidden + (size_t)srow * H_ + kc + sc0 + 4);
    *(f32x4*)&Ws[srow][sc0]     = *(const f32x4*)(w1 + (size_t)(hbase + srow) * H_ + kc + sc0);
    *(f32x4*)&Ws[srow][sc0 + 4] = *(const f32x4*)(w1 + (size_t)(hbase + srow) * H_ + kc + sc0 + 4);
    __syncthreads();
#pragma unroll
    for (int kk = 0; kk < 32; ++kk) {
      float a[4], w4[4];
#pragma unroll
      for (int i = 0; i < 4; ++i) a[i] = hs[bb * 4 + i][kk];
#pragma unroll
      for (int j = 0; j < 4; ++j) w4[j] = Ws[hb + 16 * j][kk];
#pragma unroll
      for (int i = 0; i < 4; ++i)
#pragma unroll
        for (int j = 0; j < 4; ++j) acc[i][j] += a[i] * w4[j];
    }
    __syncthreads();
  }
#pragma unroll
  for (int i = 0; i < 4; ++i)
#pragma unroll
    for (int j = 0; j < 4; ++j) {
      int h = hbase + hb + 16 * j;
      hx[(size_t)(bb * 4 + i) * H_ + h] = acc[i][j] + b1[h] + b2[h];
    }
}

// ---------------- attention GEMM: 128x128, BK=32, dbuf 1-barrier, T2 swizzle -
// Staging identical footprint to round-4 (64B per row per 4 lanes, coalesced);
// 16B chunks permuted within each row: slot x holds global chunk x ^ ((row>>1)&3).
// Read at xoff = (l4 ^ ((l15>>1)&3))*8 -> 2-way banks (free). One s_barrier +
// explicit vmcnt(0) per K-step; stage of next tile overlaps MFMA of current.
__global__ __launch_bounds__(256) void k_attn_bf(const unsigned short* __restrict__ encbf,
                                                 const unsigned short* __restrict__ bw,
                                                 const float* __restrict__ hx,
                                                 const float* __restrict__ vw,
                                                 float* __restrict__ epart) {
  __shared__ unsigned short As[2][4096];   // 2 x 8KB
  __shared__ unsigned short Bs[2][4096];   // 2 x 8KB
  const int bid = blockIdx.x;              // 2048
  const int xcd = bid & 7, idx = bid >> 3;
  const int bm = xcd * 32 + (idx >> 3);    // XCD x owns bm x*32..x*32+31
  const int bn = idx & 7;                  // bn-inner: A-panel reuse on-XCD
  const int t = threadIdx.x;
  const int l = t & 63, w = t >> 6;
  const int wr = w >> 1, wc = w & 1;
  const int l15 = l & 15, l4 = l >> 4;

  f32x4 acc[4][4] = {};

  const unsigned short* Ag = encbf + (size_t)(bm * 128) * M_;
  const unsigned short* Bg = bw + (size_t)(bn * 128) * M_;

  // stage: row = t>>2 (+64 for 2nd instr), chunk permuted within 64B row
  const int srow = t >> 2;
  const int sc = ((t & 3) ^ ((t >> 3) & 3)) * 8;
  const unsigned short* ApT = Ag + (size_t)srow * M_ + sc;
  const unsigned short* BpT = Bg + (size_t)srow * M_ + sc;
  // read: chunk xor, uniform across m/n fragments
  const int xoff = (l4 ^ ((l15 >> 1) & 3)) * 8;

#define STAGE(buf, kt) do { const int k0 = (kt) * 32;                    \
    async16(ApT + k0,             &As[buf][0]    + (size_t)t * 8);       \
    async16(ApT + 64 * M_ + k0,   &As[buf][2048] + (size_t)t * 8);       \
    async16(BpT + k0,             &Bs[buf][0]    + (size_t)t * 8);       \
    async16(BpT + 64 * M_ + k0,   &Bs[buf][2048] + (size_t)t * 8); } while (0)

  STAGE(0, 0);
  asm volatile("s_waitcnt vmcnt(0)" ::: "memory");
  __builtin_amdgcn_s_barrier();

  for (int kt = 0; kt < 64; ++kt) {
    const int cur = kt & 1;
    if (kt < 63) STAGE(cur ^ 1, kt + 1);
    short8 af[4], bf[4];
#pragma unroll
    for (int m = 0; m < 4; ++m)
      af[m] = *(const short8*)(&As[cur][(wr * 64 + m * 16 + l15) * 32 + xoff]);
#pragma unroll
    for (int n = 0; n < 4; ++n)
      bf[n] = *(const short8*)(&Bs[cur][(wc * 64 + n * 16 + l15) * 32 + xoff]);
#pragma unroll
    for (int m = 0; m < 4; ++m)
#pragma unroll
      for (int n = 0; n < 4; ++n)
        acc[m][n] = __builtin_amdgcn_mfma_f32_16x16x32_bf16(af[m], bf[n], acc[m][n], 0, 0, 0);
    asm volatile("s_waitcnt vmcnt(0)" ::: "memory");
    __builtin_amdgcn_s_barrier();
  }
#undef STAGE

  const int colbase = bn * 128 + wc * 64;
#pragma unroll
  for (int m = 0; m < 4; ++m) {
#pragma unroll
    for (int j = 0; j < 4; ++j) {
      int rloc = wr * 64 + m * 16 + l4 * 4 + j;
      int rg = bm * 128 + rloc;
      int b = rg >> 9;
      float sum = 0.f;
#pragma unroll
      for (int n = 0; n < 4; ++n) {
        int h = colbase + n * 16 + l15;
        sum += vw[h] * tanhf(hx[b * H_ + h] + acc[m][n][j]);
      }
      sum += __shfl_xor(sum, 1);
      sum += __shfl_xor(sum, 2);
      sum += __shfl_xor(sum, 4);
      sum += __shfl_xor(sum, 8);
      if (l15 == 0) epart[(size_t)(bn * 2 + wc) * BS_ + rg] = sum;
    }
  }
}

// ---------------- attention GEMM (slow fallback: fused f32 A conversion) ----
__global__ __launch_bounds__(256) void k_attn(const float* __restrict__ enc,
                                              const unsigned short* __restrict__ bw,
                                              const float* __restrict__ hx,
                                              const float* __restrict__ vw,
                                              float* __restrict__ epart) {
  __shared__ unsigned short As[128 * 32];
  __shared__ unsigned short Bs[128 * 32];
  const int bid = blockIdx.x;
  const int bm = bid & 255, bn = bid >> 8;
  const int t = threadIdx.x;
  const int l = t & 63, w = t >> 6;
  const int wr = w >> 1, wc = w & 1;
  const int l15 = l & 15, l4 = l >> 4;

  f32x4 acc[4][4] = {};

  const float* Ag = enc + (size_t)(bm * 128) * M_;
  const unsigned short* Bg = bw + (size_t)(bn * 128) * M_;

  const int ar = t >> 3;
  const int ac = (t & 7) * 4;
  const int br = t >> 2;
  const int bc = (t & 3) * 8;

  for (int kt = 0; kt < 64; ++kt) {
    const int k0 = kt * 32;
    async16(Bg + (size_t)br * M_ + k0 + bc, (char*)Bs + (size_t)t * 16);
    async16(Bg + (size_t)(br + 64) * M_ + k0 + bc, (char*)Bs + 4096 + (size_t)t * 16);
#pragma unroll
    for (int j = 0; j < 4; ++j) {
      f32x4 v = *(const f32x4*)(Ag + (size_t)(ar + j * 32) * M_ + k0 + ac);
      ushort4 o = { f2bf(v.x), f2bf(v.y), f2bf(v.z), f2bf(v.w) };
      *(ushort4*)(As + (ar + j * 32) * 32 + ac) = o;
    }
    __syncthreads();
    short8 af[4], bf[4];
#pragma unroll
    for (int m = 0; m < 4; ++m)
      af[m] = *(const short8*)(As + (wr * 64 + m * 16 + l15) * 32 + l4 * 8);
#pragma unroll
    for (int n = 0; n < 4; ++n)
      bf[n] = *(const short8*)(Bs + (wc * 64 + n * 16 + l15) * 32 + l4 * 8);
#pragma unroll
    for (int m = 0; m < 4; ++m)
#pragma unroll
      for (int n = 0; n < 4; ++n)
        acc[m][n] = __builtin_amdgcn_mfma_f32_16x16x32_bf16(af[m], bf[n], acc[m][n], 0, 0, 0);
    __syncthreads();
  }

  const int colbase = bn * 128 + wc * 64;
#pragma unroll
  for (int m = 0; m < 4; ++m) {
#pragma unroll
    for (int j = 0; j < 4; ++j) {
      int rloc = wr * 64 + m * 16 + l4 * 4 + j;
      int rg = bm * 128 + rloc;
      int b = rg >> 9;
      float sum = 0.f;
#pragma unroll
      for (int n = 0; n < 4; ++n) {
        int h = colbase + n * 16 + l15;
        sum += vw[h] * tanhf(hx[b * H_ + h] + acc[m][n][j]);
      }
      sum += __shfl_xor(sum, 1);
      sum += __shfl_xor(sum, 2);
      sum += __shfl_xor(sum, 4);
      sum += __shfl_xor(sum, 8);
      if (l15 == 0) epart[(size_t)(bn * 2 + wc) * BS_ + rg] = sum;
    }
  }
}

// ---------------- softmax over S per batch row (reduces 16 e-partials) ------
__global__ __launch_bounds__(256) void k_softmax(const float* __restrict__ epart,
                                                 float* __restrict__ score) {
  int b = blockIdx.x, t = threadIdx.x;
  float v0 = 0.f, v1 = 0.f;
#pragma unroll
  for (int p = 0; p < 16; ++p) {
    v0 += epart[(size_t)p * BS_ + b * S_ + t];
    v1 += epart[(size_t)p * BS_ + b * S_ + 256 + t];
  }
  int w = t >> 6, l = t & 63;
  float m = fmaxf(v0, v1);
#pragma unroll
  for (int off = 32; off; off >>= 1) m = fmaxf(m, __shfl_xor(m, off));
  __shared__ float sm[4];
  __shared__ float ssum[4];
  if (l == 0) sm[w] = m;
  __syncthreads();
  float M = fmaxf(fmaxf(sm[0], sm[1]), fmaxf(sm[2], sm[3]));
  float p0 = expf(v0 - M), p1 = expf(v1 - M);
  float s = p0 + p1;
#pragma unroll
  for (int off = 32; off; off >>= 1) s += __shfl_xor(s, off);
  if (l == 0) ssum[w] = s;
  __syncthreads();
  float inv = 1.f / (ssum[0] + ssum[1] + ssum[2] + ssum[3]);
  score[b * S_ + t] = p0 * inv;
  score[b * S_ + 256 + t] = p1 * inv;
}

// ---------------- context partials (bf16 enc read) ----------------
__global__ __launch_bounds__(256) void k_ctxb(const unsigned short* __restrict__ encbf,
                                              const float* __restrict__ score,
                                              float* __restrict__ cpart) {
  int blk = blockIdx.x;            // 512 = b(64) x sc(8)
  int b = blk >> 3, sc = blk & 7;
  int t = threadIdx.x;
  int m = t * 8;
  f32x4 acc0 = {0.f, 0.f, 0.f, 0.f}, acc1 = {0.f, 0.f, 0.f, 0.f};
  const unsigned short* ep = encbf + (size_t)(b * S_ + sc * 64) * M_ + m;
  const float* sp = score + b * S_ + sc * 64;
#pragma unroll 4
  for (int s8 = 0; s8 < 64; ++s8) {
    float sv = sp[s8];
    short8 v = *(const short8*)(ep + (size_t)s8 * M_);
    acc0.x += bf2f((unsigned short)v[0]) * sv;
    acc0.y += bf2f((unsigned short)v[1]) * sv;
    acc0.z += bf2f((unsigned short)v[2]) * sv;
    acc0.w += bf2f((unsigned short)v[3]) * sv;
    acc1.x += bf2f((unsigned short)v[4]) * sv;
    acc1.y += bf2f((unsigned short)v[5]) * sv;
    acc1.z += bf2f((unsigned short)v[6]) * sv;
    acc1.w += bf2f((unsigned short)v[7]) * sv;
  }
  float* dst = cpart + (size_t)sc * (B_ * M_) + b * M_ + m;
  *(f32x4*)dst = acc0;
  *(f32x4*)(dst + 4) = acc1;
}

// ---------------- context partials (f32 fallback) ----------------
__global__ __launch_bounds__(256) void k_ctx(const float* __restrict__ enc,
                                             const float* __restrict__ score,
                                             float* __restrict__ cpart) {
  int blk = blockIdx.x;
  int b = blk >> 4, mc = (blk >> 3) & 1, sc = blk & 7;
  int t = threadIdx.x;
  int m = mc * 1024 + t * 4;
  f32x4 acc = {0.f, 0.f, 0.f, 0.f};
  const float* ep = enc + (size_t)b * S_ * M_ + m;
  const float* sp = score + b * S_ + sc * 64;
#pragma unroll 4
  for (int s8 = 0; s8 < 64; ++s8) {
    float sv = sp[s8];
    f32x4 v = *(const f32x4*)(ep + (size_t)(sc * 64 + s8) * M_);
    acc += v * sv;
  }
  *(f32x4*)(cpart + (size_t)sc * (B_ * M_) + b * M_ + m) = acc;
}

__global__ void k_ctxred(const float* __restrict__ cpart, float* __restrict__ ctx) {
  int i0 = (blockIdx.x * 256 + threadIdx.x) * 4;
  f32x4 a = {0.f, 0.f, 0.f, 0.f};
#pragma unroll
  for (int p = 0; p < 8; ++p) a += *(const f32x4*)(cpart + (size_t)p * (B_ * M_) + i0);
  *(f32x4*)(ctx + i0) = a;
}

// ---------------- GRU GEMMs: 64x64 tile, 4x4/thread, K-split x2 -------------
__global__ __launch_bounds__(256) void k_grugemm(const float* __restrict__ ctx,
                                                 const float* __restrict__ wv,
                                                 const float* __restrict__ hidden,
                                                 const float* __restrict__ Wih,
                                                 const float* __restrict__ bih,
                                                 const float* __restrict__ Whh,
                                                 const float* __restrict__ bhh,
                                                 float* __restrict__ gi0,
                                                 float* __restrict__ gi1,
                                                 float* __restrict__ gh0,
                                                 float* __restrict__ gh1) {
  __shared__ float xs[64][36];
  __shared__ float Ws[64][36];
  const int t = threadIdx.x;
  const int blk = blockIdx.x;
  const bool ghh = blk >= 96;
  const int sub = ghh ? blk - 96 : blk;
  const int colt = sub % 48, half = sub / 48;
  const int gbase = colt * 64;
  const int K = ghh ? H_ : XIN_;
  const int klo = ghh ? (half ? 512 : 0) : (half ? 1280 : 0);
  const int khi = ghh ? (half ? 1024 : 512) : (half ? 2560 : 1280);
  const float* Wp = ghh ? Whh : Wih;
  const int vb = t & 15, bb = t >> 4;
  const int srow = t >> 2, sc0 = (t & 3) * 8;
  float acc[4][4] = {};
  for (int kc = klo; kc < khi; kc += 32) {
    f32x4 xa, xb;
    if (ghh) {
      xa = *(const f32x4*)(hidden + (size_t)srow * H_ + kc + sc0);
      xb = *(const f32x4*)(hidden + (size_t)srow * H_ + kc + sc0 + 4);
    } else if (kc + sc0 < M_) {
      xa = *(const f32x4*)(ctx + (size_t)srow * M_ + kc + sc0);
      xb = *(const f32x4*)(ctx + (size_t)srow * M_ + kc + sc0 + 4);
    } else {
      xa = *(const f32x4*)(wv + (size_t)srow * E_ + kc + sc0 - M_);
      xb = *(const f32x4*)(wv + (size_t)srow * E_ + kc + sc0 - M_ + 4);
    }
    *(f32x4*)&xs[srow][sc0] = xa;
    *(f32x4*)&xs[srow][sc0 + 4] = xb;
    *(f32x4*)&Ws[srow][sc0]     = *(const f32x4*)(Wp + (size_t)(gbase + srow) * K + kc + sc0);
    *(f32x4*)&Ws[srow][sc0 + 4] = *(const f32x4*)(Wp + (size_t)(gbase + srow) * K + kc + sc0 + 4);
    __syncthreads();
#pragma unroll
    for (int kk = 0; kk < 32; ++kk) {
      float a[4], w4[4];
#pragma unroll
      for (int i = 0; i < 4; ++i) a[i] = xs[bb * 4 + i][kk];
#pragma unroll
      for (int j = 0; j < 4; ++j) w4[j] = Ws[vb + 16 * j][kk];
#pragma unroll
      for (int i = 0; i < 4; ++i)
#pragma unroll
        for (int j = 0; j < 4; ++j) acc[i][j] += a[i] * w4[j];
    }
    __syncthreads();
  }
  float* dst = ghh ? (half ? gh1 : gh0) : (half ? gi1 : gi0);
  const float* bias = ghh ? bhh : bih;
#pragma unroll
  for (int i = 0; i < 4; ++i)
#pragma unroll
    for (int j = 0; j < 4; ++j) {
      int g = gbase + vb + 16 * j;
      float v = acc[i][j] + (half ? 0.f : bias[g]);
      dst[(size_t)(bb * 4 + i) * G3_ + g] = v;
    }
}

// ---------------- GRU gates -> new_hidden (f32 + bf16 copy) ----------------
__global__ void k_gate(const float* __restrict__ gi0, const float* __restrict__ gi1,
                       const float* __restrict__ gh0, const float* __restrict__ gh1,
                       const float* __restrict__ hidden, float* __restrict__ newh,
                       unsigned short* __restrict__ newhbf) {
  int o = blockIdx.x * 256 + threadIdx.x;
  int b = o >> 10, h = o & 1023;
  size_t base = (size_t)b * G3_;
  float ir = gi0[base + h] + gi1[base + h];
  float iz = gi0[base + 1024 + h] + gi1[base + 1024 + h];
  float in = gi0[base + 2048 + h] + gi1[base + 2048 + h];
  float hr = gh0[base + h] + gh1[base + h];
  float hz = gh0[base + 1024 + h] + gh1[base + 1024 + h];
  float hn = gh0[base + 2048 + h] + gh1[base + 2048 + h];
  float r = 1.f / (1.f + expf(-(ir + hr)));
  float z = 1.f / (1.f + expf(-(iz + hz)));
  float n = tanhf(in + r * hn);
  float nh = (1.f - z) * n + z * hidden[o];
  newh[o] = nh;
  newhbf[o] = f2bf(nh);
}

// ---------------- output projection: bf16 MFMA, 64x128 tile ----------------
__global__ __launch_bounds__(256) void k_outproj_mfma(const unsigned short* __restrict__ newhbf,
                                                      const float* __restrict__ ow,
                                                      const float* __restrict__ ob,
                                                      float* __restrict__ pred) {
  __shared__ unsigned short As[2048];   // 4 KB
  __shared__ unsigned short Bs[4096];   // 8 KB
  const int t = threadIdx.x;
  const int w = t >> 6, l = t & 63;
  const int l15 = l & 15, l4 = l >> 4;
  const int vbase = blockIdx.x * 128;   // 250 blocks

  const unsigned short* aSrc = newhbf + (size_t)(t & 63) * H_ + (t >> 6) * 8;
  const int br = t >> 1, bh = t & 1;
  const float* bSrc = ow + (size_t)(vbase + br) * H_ + bh * 16;

  f32x4 acc[4][2] = {};

  for (int kc = 0; kc < H_; kc += 32) {
    async16(aSrc + kc, (char*)As + (size_t)t * 16);
    f32x4 v0 = *(const f32x4*)(bSrc + kc);
    f32x4 v1 = *(const f32x4*)(bSrc + kc + 4);
    f32x4 v2 = *(const f32x4*)(bSrc + kc + 8);
    f32x4 v3 = *(const f32x4*)(bSrc + kc + 12);
    ushort4 p0 = { f2bf(v0.x), f2bf(v0.y), f2bf(v0.z), f2bf(v0.w) };
    ushort4 p1 = { f2bf(v1.x), f2bf(v1.y), f2bf(v1.z), f2bf(v1.w) };
    ushort4 p2 = { f2bf(v2.x), f2bf(v2.y), f2bf(v2.z), f2bf(v2.w) };
    ushort4 p3 = { f2bf(v3.x), f2bf(v3.y), f2bf(v3.z), f2bf(v3.w) };
    const int kg0 = bh * 2;
    *(ushort4*)(Bs + kg0 * 1024 + br * 8)       = p0;
    *(ushort4*)(Bs + kg0 * 1024 + br * 8 + 4)   = p1;
    *(ushort4*)(Bs + (kg0 + 1) * 1024 + br * 8)     = p2;
    *(ushort4*)(Bs + (kg0 + 1) * 1024 + br * 8 + 4) = p3;
    __syncthreads();
    short8 af[4], bf[2];
#pragma unroll
    for (int rf = 0; rf < 4; ++rf)
      af[rf] = *(const short8*)(As + l4 * 512 + (rf * 16 + l15) * 8);
#pragma unroll
    for (int cf = 0; cf < 2; ++cf)
      bf[cf] = *(const short8*)(Bs + l4 * 1024 + (w * 32 + cf * 16 + l15) * 8);
#pragma unroll
    for (int rf = 0; rf < 4; ++rf)
#pragma unroll
      for (int cf = 0; cf < 2; ++cf)
        acc[rf][cf] = __builtin_amdgcn_mfma_f32_16x16x32_bf16(af[rf], bf[cf], acc[rf][cf], 0, 0, 0);
    __syncthreads();
  }

#pragma unroll
  for (int cf = 0; cf < 2; ++cf) {
    int col = vbase + w * 32 + cf * 16 + l15;
    float bias = ob[col];
#pragma unroll
    for (int rf = 0; rf < 4; ++rf)
#pragma unroll
      for (int j = 0; j < 4; ++j) {
        int row = rf * 16 + l4 * 4 + j;
        pred[(size_t)row * V_ + col] = acc[rf][cf][j] + bias;
      }
  }
}

extern "C" void kernel_launch(void* const* d_in, const int* in_sizes, int n_in,
                              void* d_out, int out_size, void* d_ws, size_t ws_size,
                              hipStream_t stream) {
  const int*   word   = (const int*)d_in[0];
  const float* hidden = (const float*)d_in[1];
  const float* enc    = (const float*)d_in[2];
  const float* emb    = (const float*)d_in[5];
  const float* lin1w  = (const float*)d_in[6];
  const float* lin1b  = (const float*)d_in[7];
  const float* lin2w  = (const float*)d_in[8];
  const float* lin2b  = (const float*)d_in[9];
  const float* vw     = (const float*)d_in[10];
  const float* Wih    = (const float*)d_in[12];
  const float* bih    = (const float*)d_in[13];
  const float* Whh    = (const float*)d_in[14];
  const float* bhh    = (const float*)d_in[15];
  const float* ow     = (const float*)d_in[16];
  const float* ob     = (const float*)d_in[17];

  float* out   = (float*)d_out;
  float* pred  = out;                   // [64][32000]
  float* newh  = out + 2048000;         // [64][1024]
  float* score = out + 2113536;         // [64][512]

  const size_t ENCBF = 134217728;       // 32768*2048*2
  const bool fast = ws_size >= ENCBF + 13107200;
  char* ws = (char*)d_ws;
  unsigned short* encbf = (unsigned short*)ws;      // fast path only
  size_t base = fast ? ENCBF : 0;
  unsigned short* bw = (unsigned short*)(ws + base);        // 4,194,304
  float* hx    = (float*)(ws + base + 4194304);             // 262,144
  float* wvbuf = (float*)(ws + base + 4456448);             // 131,072
  float* epart = (float*)(ws + base + 4587520);             // 2,097,152
  float* cpart = (float*)(ws + base + 6684672);             // 4,194,304
  float* ctx   = (float*)(ws + base + 10878976);            // 524,288
  float* gi0   = (float*)(ws + base + 11403264);            // 786,432
  float* gh0   = (float*)(ws + base + 12189696);            // 786,432
  unsigned short* nhbf = (unsigned short*)(ws + base + 12976128);  // 131,072
  // gi1/gh1 reuse the dead epart region (epart consumed by k_softmax before
  // k_grugemm runs; stream-serialized)
  float* gi1   = epart;                                     // 786,432
  float* gh1   = epart + 196608;                            // 786,432

  k_hx<<<16, 256, 0, stream>>>(hidden, lin1w, lin1b, lin2b, hx);
  if (fast) {
    k_conv<<<4096, 256, 0, stream>>>(enc, encbf, lin2w, bw, word, emb, wvbuf);
    k_attn_bf<<<2048, 256, 0, stream>>>(encbf, bw, hx, vw, epart);
    k_softmax<<<64, 256, 0, stream>>>(epart, score);
    k_ctxb<<<512, 256, 0, stream>>>(encbf, score, cpart);
  } else {
    k_conv<<<4096, 256, 0, stream>>>(enc, encbf, lin2w, bw, word, emb, wvbuf); // enc part unused
    k_attn<<<2048, 256, 0, stream>>>(enc, bw, hx, vw, epart);
    k_softmax<<<64, 256, 0, stream>>>(epart, score);
    k_ctx<<<1024, 256, 0, stream>>>(enc, score, cpart);
  }
  k_ctxred<<<128, 256, 0, stream>>>(cpart, ctx);
  k_grugemm<<<192, 256, 0, stream>>>(ctx, wvbuf, hidden, Wih, bih, Whh, bhh, gi0, gi1, gh0, gh1);
  k_gate<<<256, 256, 0, stream>>>(gi0, gi1, gh0, gh1, hidden, newh, nhbf);
  k_outproj_mfma<<<250, 256, 0, stream>>>(nhbf, ow, ob, pred);
}

// Round 7
// 503.413 us; speedup vs baseline: 1.2399x; 1.0152x over previous
//
#include <hip/hip_runtime.h>
#include <hip/hip_bf16.h>
#include <stdint.h>

typedef __attribute__((ext_vector_type(4))) float f32x4;
typedef __attribute__((ext_vector_type(8))) short short8;

#define B_   64
#define S_   512
#define H_   1024
#define E_   512
#define V_   32000
#define M_   2048            // D*H
#define BS_  32768           // B*S
#define XIN_ 2560            // M_+E_
#define G3_  3072

__device__ __forceinline__ unsigned short f2bf(float f) {
  union { float f; unsigned u; } x; x.f = f;
  unsigned r = x.u + 0x7fffu + ((x.u >> 16) & 1u);
  return (unsigned short)(r >> 16);
}

__device__ __forceinline__ float bf2f(unsigned short u) {
  union { unsigned u; float f; } x; x.u = (unsigned)u << 16; return x.f;
}

__device__ __forceinline__ void async16(const void* g, void* l) {
  __builtin_amdgcn_global_load_lds((const __attribute__((address_space(1))) unsigned*)g,
                                   (__attribute__((address_space(3))) unsigned*)l,
                                   16, 0, 0);
}

// ------- merged converter: enc->bf16 (16B stores), lin2_w->bf16, emb gather --
__global__ __launch_bounds__(256) void k_conv(const float* __restrict__ enc,
                                              unsigned short* __restrict__ ebf,
                                              const float* __restrict__ lin2w,
                                              unsigned short* __restrict__ bw,
                                              const int* __restrict__ word,
                                              const float* __restrict__ emb,
                                              float* __restrict__ wv) {
  const size_t NENC8 = (size_t)BS_ * M_ / 8;   // 8,388,608
  const size_t NW8   = (size_t)H_ * M_ / 8;    // 262,144
  const size_t NWV4  = (size_t)B_ * E_ / 4;    // 8,192
  const size_t total = NENC8 + NW8 + NWV4;
  for (size_t idx = (size_t)blockIdx.x * 256 + threadIdx.x; idx < total;
       idx += (size_t)gridDim.x * 256) {
    if (idx < NENC8) {
      f32x4 a = *(const f32x4*)(enc + idx * 8);
      f32x4 b = *(const f32x4*)(enc + idx * 8 + 4);
      short8 o = { (short)f2bf(a.x), (short)f2bf(a.y), (short)f2bf(a.z), (short)f2bf(a.w),
                   (short)f2bf(b.x), (short)f2bf(b.y), (short)f2bf(b.z), (short)f2bf(b.w) };
      *(short8*)(ebf + idx * 8) = o;
    } else if (idx < NENC8 + NW8) {
      size_t i = idx - NENC8;
      f32x4 a = *(const f32x4*)(lin2w + i * 8);
      f32x4 b = *(const f32x4*)(lin2w + i * 8 + 4);
      short8 o = { (short)f2bf(a.x), (short)f2bf(a.y), (short)f2bf(a.z), (short)f2bf(a.w),
                   (short)f2bf(b.x), (short)f2bf(b.y), (short)f2bf(b.z), (short)f2bf(b.w) };
      *(short8*)(bw + i * 8) = o;
    } else {
      size_t i = idx - NENC8 - NW8;     // < 8192
      int i0 = (int)i * 4;
      int b = i0 >> 9, c = i0 & 511;
      f32x4 v = *(const f32x4*)(emb + (size_t)word[b] * E_ + c);
      *(f32x4*)(wv + i0) = v;
    }
  }
}

// ---------------- h_x = hidden @ lin1_w.T + b1 + b2 (LDS-tiled 64x64) -------
__global__ __launch_bounds__(256) void k_hx(const float* __restrict__ hidden,
                                            const float* __restrict__ w1,
                                            const float* __restrict__ b1,
                                            const float* __restrict__ b2,
                                            float* __restrict__ hx) {
  __shared__ float hs[64][36];
  __shared__ float Ws[64][36];
  const int t = threadIdx.x;
  const int hbase = blockIdx.x * 64;     // 16 blocks
  const int hb = t & 15, bb = t >> 4;
  const int srow = t >> 2, sc0 = (t & 3) * 8;
  float acc[4][4] = {};
  for (int kc = 0; kc < H_; kc += 32) {
    *(f32x4*)&hs[srow][sc0]     = *(const f32x4*)(hidden + (size_t)srow * H_ + kc + sc0);
    *(f32x4*)&hs[srow][sc0 + 4] = *(const f32x4*)(hidden + (size_t)srow * H_ + kc + sc0 + 4);
    *(f32x4*)&Ws[srow][sc0]     = *(const f32x4*)(w1 + (size_t)(hbase + srow) * H_ + kc + sc0);
    *(f32x4*)&Ws[srow][sc0 + 4] = *(const f32x4*)(w1 + (size_t)(hbase + srow) * H_ + kc + sc0 + 4);
    __syncthreads();
#pragma unroll
    for (int kk = 0; kk < 32; ++kk) {
      float a[4], w4[4];
#pragma unroll
      for (int i = 0; i < 4; ++i) a[i] = hs[bb * 4 + i][kk];
#pragma unroll
      for (int j = 0; j < 4; ++j) w4[j] = Ws[hb + 16 * j][kk];
#pragma unroll
      for (int i = 0; i < 4; ++i)
#pragma unroll
        for (int j = 0; j < 4; ++j) acc[i][j] += a[i] * w4[j];
    }
    __syncthreads();
  }
#pragma unroll
  for (int i = 0; i < 4; ++i)
#pragma unroll
    for (int j = 0; j < 4; ++j) {
      int h = hbase + hb + 16 * j;
      hx[(size_t)(bb * 4 + i) * H_ + h] = acc[i][j] + b1[h] + b2[h];
    }
}

// ---------------- attention GEMM: 128x128, BK=32, 3-buf depth-2 pipeline ----
// T4 counted vmcnt: stage(kt+2) issued each step, wait vmcnt(4) -> only the
// oldest stage (kt+1) must land; newest 4 loads stay in flight across the
// barrier. T2 chunk-xor swizzle (conflicts=0, coalescing preserved, r6).
__global__ __launch_bounds__(256) void k_attn_bf(const unsigned short* __restrict__ encbf,
                                                 const unsigned short* __restrict__ bw,
                                                 const float* __restrict__ hx,
                                                 const float* __restrict__ vw,
                                                 float* __restrict__ epart) {
  __shared__ unsigned short As[3][4096];   // 3 x 8KB
  __shared__ unsigned short Bs[3][4096];   // 3 x 8KB
  const int bid = blockIdx.x;              // 2048
  const int xcd = bid & 7, idx = bid >> 3;
  const int bm = xcd * 32 + (idx >> 3);    // XCD x owns bm x*32..x*32+31
  const int bn = idx & 7;                  // bn-inner: A-panel reuse on-XCD
  const int t = threadIdx.x;
  const int l = t & 63, w = t >> 6;
  const int wr = w >> 1, wc = w & 1;
  const int l15 = l & 15, l4 = l >> 4;

  f32x4 acc[4][4] = {};

  const unsigned short* Ag = encbf + (size_t)(bm * 128) * M_;
  const unsigned short* Bg = bw + (size_t)(bn * 128) * M_;

  // stage: row = t>>2 (+64 for 2nd instr), chunk permuted within 64B row
  const int srow = t >> 2;
  const int sc = ((t & 3) ^ ((t >> 3) & 3)) * 8;
  const unsigned short* ApT = Ag + (size_t)srow * M_ + sc;
  const unsigned short* BpT = Bg + (size_t)srow * M_ + sc;
  // read: chunk xor, uniform across m/n fragments
  const int xoff = (l4 ^ ((l15 >> 1) & 3)) * 8;

#define STAGE(buf, kt) do { const int k0 = (kt) * 32;                    \
    async16(ApT + k0,             &As[buf][0]    + (size_t)t * 8);       \
    async16(ApT + 64 * M_ + k0,   &As[buf][2048] + (size_t)t * 8);       \
    async16(BpT + k0,             &Bs[buf][0]    + (size_t)t * 8);       \
    async16(BpT + 64 * M_ + k0,   &Bs[buf][2048] + (size_t)t * 8); } while (0)

  STAGE(0, 0);
  STAGE(1, 1);
  asm volatile("s_waitcnt vmcnt(4)" ::: "memory");   // stage(0) landed
  __builtin_amdgcn_s_barrier();

  int cur = 0;
  for (int kt = 0; kt < 64; ++kt) {
    int nx2 = cur + 2; if (nx2 >= 3) nx2 -= 3;
    if (kt < 62) STAGE(nx2, kt + 2);
    short8 af[4], bf[4];
#pragma unroll
    for (int m = 0; m < 4; ++m)
      af[m] = *(const short8*)(&As[cur][(wr * 64 + m * 16 + l15) * 32 + xoff]);
#pragma unroll
    for (int n = 0; n < 4; ++n)
      bf[n] = *(const short8*)(&Bs[cur][(wc * 64 + n * 16 + l15) * 32 + xoff]);
#pragma unroll
    for (int m = 0; m < 4; ++m)
#pragma unroll
      for (int n = 0; n < 4; ++n)
        acc[m][n] = __builtin_amdgcn_mfma_f32_16x16x32_bf16(af[m], bf[n], acc[m][n], 0, 0, 0);
    if (kt < 62) {
      asm volatile("s_waitcnt vmcnt(4)" ::: "memory");  // stage(kt+1) landed
    } else {
      asm volatile("s_waitcnt vmcnt(0)" ::: "memory");  // drain tail
    }
    __builtin_amdgcn_s_barrier();
    cur = cur + 1; if (cur >= 3) cur = 0;
  }
#undef STAGE

  const int colbase = bn * 128 + wc * 64;
#pragma unroll
  for (int m = 0; m < 4; ++m) {
#pragma unroll
    for (int j = 0; j < 4; ++j) {
      int rloc = wr * 64 + m * 16 + l4 * 4 + j;
      int rg = bm * 128 + rloc;
      int b = rg >> 9;
      float sum = 0.f;
#pragma unroll
      for (int n = 0; n < 4; ++n) {
        int h = colbase + n * 16 + l15;
        sum += vw[h] * tanhf(hx[b * H_ + h] + acc[m][n][j]);
      }
      sum += __shfl_xor(sum, 1);
      sum += __shfl_xor(sum, 2);
      sum += __shfl_xor(sum, 4);
      sum += __shfl_xor(sum, 8);
      if (l15 == 0) epart[(size_t)(bn * 2 + wc) * BS_ + rg] = sum;
    }
  }
}

// ---------------- attention GEMM (slow fallback: fused f32 A conversion) ----
__global__ __launch_bounds__(256) void k_attn(const float* __restrict__ enc,
                                              const unsigned short* __restrict__ bw,
                                              const float* __restrict__ hx,
                                              const float* __restrict__ vw,
                                              float* __restrict__ epart) {
  __shared__ unsigned short As[128 * 32];
  __shared__ unsigned short Bs[128 * 32];
  const int bid = blockIdx.x;
  const int bm = bid & 255, bn = bid >> 8;
  const int t = threadIdx.x;
  const int l = t & 63, w = t >> 6;
  const int wr = w >> 1, wc = w & 1;
  const int l15 = l & 15, l4 = l >> 4;

  f32x4 acc[4][4] = {};

  const float* Ag = enc + (size_t)(bm * 128) * M_;
  const unsigned short* Bg = bw + (size_t)(bn * 128) * M_;

  const int ar = t >> 3;
  const int ac = (t & 7) * 4;
  const int br = t >> 2;
  const int bc = (t & 3) * 8;

  for (int kt = 0; kt < 64; ++kt) {
    const int k0 = kt * 32;
    async16(Bg + (size_t)br * M_ + k0 + bc, (char*)Bs + (size_t)t * 16);
    async16(Bg + (size_t)(br + 64) * M_ + k0 + bc, (char*)Bs + 4096 + (size_t)t * 16);
#pragma unroll
    for (int j = 0; j < 4; ++j) {
      f32x4 v = *(const f32x4*)(Ag + (size_t)(ar + j * 32) * M_ + k0 + ac);
      ushort4 o = { f2bf(v.x), f2bf(v.y), f2bf(v.z), f2bf(v.w) };
      *(ushort4*)(As + (ar + j * 32) * 32 + ac) = o;
    }
    __syncthreads();
    short8 af[4], bf[4];
#pragma unroll
    for (int m = 0; m < 4; ++m)
      af[m] = *(const short8*)(As + (wr * 64 + m * 16 + l15) * 32 + l4 * 8);
#pragma unroll
    for (int n = 0; n < 4; ++n)
      bf[n] = *(const short8*)(Bs + (wc * 64 + n * 16 + l15) * 32 + l4 * 8);
#pragma unroll
    for (int m = 0; m < 4; ++m)
#pragma unroll
      for (int n = 0; n < 4; ++n)
        acc[m][n] = __builtin_amdgcn_mfma_f32_16x16x32_bf16(af[m], bf[n], acc[m][n], 0, 0, 0);
    __syncthreads();
  }

  const int colbase = bn * 128 + wc * 64;
#pragma unroll
  for (int m = 0; m < 4; ++m) {
#pragma unroll
    for (int j = 0; j < 4; ++j) {
      int rloc = wr * 64 + m * 16 + l4 * 4 + j;
      int rg = bm * 128 + rloc;
      int b = rg >> 9;
      float sum = 0.f;
#pragma unroll
      for (int n = 0; n < 4; ++n) {
        int h = colbase + n * 16 + l15;
        sum += vw[h] * tanhf(hx[b * H_ + h] + acc[m][n][j]);
      }
      sum += __shfl_xor(sum, 1);
      sum += __shfl_xor(sum, 2);
      sum += __shfl_xor(sum, 4);
      sum += __shfl_xor(sum, 8);
      if (l15 == 0) epart[(size_t)(bn * 2 + wc) * BS_ + rg] = sum;
    }
  }
}

// ---------------- softmax over S per batch row (reduces 16 e-partials) ------
__global__ __launch_bounds__(256) void k_softmax(const float* __restrict__ epart,
                                                 float* __restrict__ score) {
  int b = blockIdx.x, t = threadIdx.x;
  float v0 = 0.f, v1 = 0.f;
#pragma unroll
  for (int p = 0; p < 16; ++p) {
    v0 += epart[(size_t)p * BS_ + b * S_ + t];
    v1 += epart[(size_t)p * BS_ + b * S_ + 256 + t];
  }
  int w = t >> 6, l = t & 63;
  float m = fmaxf(v0, v1);
#pragma unroll
  for (int off = 32; off; off >>= 1) m = fmaxf(m, __shfl_xor(m, off));
  __shared__ float sm[4];
  __shared__ float ssum[4];
  if (l == 0) sm[w] = m;
  __syncthreads();
  float M = fmaxf(fmaxf(sm[0], sm[1]), fmaxf(sm[2], sm[3]));
  float p0 = expf(v0 - M), p1 = expf(v1 - M);
  float s = p0 + p1;
#pragma unroll
  for (int off = 32; off; off >>= 1) s += __shfl_xor(s, off);
  if (l == 0) ssum[w] = s;
  __syncthreads();
  float inv = 1.f / (ssum[0] + ssum[1] + ssum[2] + ssum[3]);
  score[b * S_ + t] = p0 * inv;
  score[b * S_ + 256 + t] = p1 * inv;
}

// ---------------- context partials (bf16 enc read) ----------------
__global__ __launch_bounds__(256) void k_ctxb(const unsigned short* __restrict__ encbf,
                                              const float* __restrict__ score,
                                              float* __restrict__ cpart) {
  int blk = blockIdx.x;            // 512 = b(64) x sc(8)
  int b = blk >> 3, sc = blk & 7;
  int t = threadIdx.x;
  int m = t * 8;
  f32x4 acc0 = {0.f, 0.f, 0.f, 0.f}, acc1 = {0.f, 0.f, 0.f, 0.f};
  const unsigned short* ep = encbf + (size_t)(b * S_ + sc * 64) * M_ + m;
  const float* sp = score + b * S_ + sc * 64;
#pragma unroll 4
  for (int s8 = 0; s8 < 64; ++s8) {
    float sv = sp[s8];
    short8 v = *(const short8*)(ep + (size_t)s8 * M_);
    acc0.x += bf2f((unsigned short)v[0]) * sv;
    acc0.y += bf2f((unsigned short)v[1]) * sv;
    acc0.z += bf2f((unsigned short)v[2]) * sv;
    acc0.w += bf2f((unsigned short)v[3]) * sv;
    acc1.x += bf2f((unsigned short)v[4]) * sv;
    acc1.y += bf2f((unsigned short)v[5]) * sv;
    acc1.z += bf2f((unsigned short)v[6]) * sv;
    acc1.w += bf2f((unsigned short)v[7]) * sv;
  }
  float* dst = cpart + (size_t)sc * (B_ * M_) + b * M_ + m;
  *(f32x4*)dst = acc0;
  *(f32x4*)(dst + 4) = acc1;
}

// ---------------- context partials (f32 fallback) ----------------
__global__ __launch_bounds__(256) void k_ctx(const float* __restrict__ enc,
                                             const float* __restrict__ score,
                                             float* __restrict__ cpart) {
  int blk = blockIdx.x;
  int b = blk >> 4, mc = (blk >> 3) & 1, sc = blk & 7;
  int t = threadIdx.x;
  int m = mc * 1024 + t * 4;
  f32x4 acc = {0.f, 0.f, 0.f, 0.f};
  const float* ep = enc + (size_t)b * S_ * M_ + m;
  const float* sp = score + b * S_ + sc * 64;
#pragma unroll 4
  for (int s8 = 0; s8 < 64; ++s8) {
    float sv = sp[s8];
    f32x4 v = *(const f32x4*)(ep + (size_t)(sc * 64 + s8) * M_);
    acc += v * sv;
  }
  *(f32x4*)(cpart + (size_t)sc * (B_ * M_) + b * M_ + m) = acc;
}

__global__ void k_ctxred(const float* __restrict__ cpart, float* __restrict__ ctx) {
  int i0 = (blockIdx.x * 256 + threadIdx.x) * 4;
  f32x4 a = {0.f, 0.f, 0.f, 0.f};
#pragma unroll
  for (int p = 0; p < 8; ++p) a += *(const f32x4*)(cpart + (size_t)p * (B_ * M_) + i0);
  *(f32x4*)(ctx + i0) = a;
}

// ---------------- GRU GEMMs: 64x64 tile, 4x4/thread, K-split x2 -------------
__global__ __launch_bounds__(256) void k_grugemm(const float* __restrict__ ctx,
                                                 const float* __restrict__ wv,
                                                 const float* __restrict__ hidden,
                                                 const float* __restrict__ Wih,
                                                 const float* __restrict__ bih,
                                                 const float* __restrict__ Whh,
                                                 const float* __restrict__ bhh,
                                                 float* __restrict__ gi0,
                                                 float* __restrict__ gi1,
                                                 float* __restrict__ gh0,
                                                 float* __restrict__ gh1) {
  __shared__ float xs[64][36];
  __shared__ float Ws[64][36];
  const int t = threadIdx.x;
  const int blk = blockIdx.x;
  const bool ghh = blk >= 96;
  const int sub = ghh ? blk - 96 : blk;
  const int colt = sub % 48, half = sub / 48;
  const int gbase = colt * 64;
  const int K = ghh ? H_ : XIN_;
  const int klo = ghh ? (half ? 512 : 0) : (half ? 1280 : 0);
  const int khi = ghh ? (half ? 1024 : 512) : (half ? 2560 : 1280);
  const float* Wp = ghh ? Whh : Wih;
  const int vb = t & 15, bb = t >> 4;
  const int srow = t >> 2, sc0 = (t & 3) * 8;
  float acc[4][4] = {};
  for (int kc = klo; kc < khi; kc += 32) {
    f32x4 xa, xb;
    if (ghh) {
      xa = *(const f32x4*)(hidden + (size_t)srow * H_ + kc + sc0);
      xb = *(const f32x4*)(hidden + (size_t)srow * H_ + kc + sc0 + 4);
    } else if (kc + sc0 < M_) {
      xa = *(const f32x4*)(ctx + (size_t)srow * M_ + kc + sc0);
      xb = *(const f32x4*)(ctx + (size_t)srow * M_ + kc + sc0 + 4);
    } else {
      xa = *(const f32x4*)(wv + (size_t)srow * E_ + kc + sc0 - M_);
      xb = *(const f32x4*)(wv + (size_t)srow * E_ + kc + sc0 - M_ + 4);
    }
    *(f32x4*)&xs[srow][sc0] = xa;
    *(f32x4*)&xs[srow][sc0 + 4] = xb;
    *(f32x4*)&Ws[srow][sc0]     = *(const f32x4*)(Wp + (size_t)(gbase + srow) * K + kc + sc0);
    *(f32x4*)&Ws[srow][sc0 + 4] = *(const f32x4*)(Wp + (size_t)(gbase + srow) * K + kc + sc0 + 4);
    __syncthreads();
#pragma unroll
    for (int kk = 0; kk < 32; ++kk) {
      float a[4], w4[4];
#pragma unroll
      for (int i = 0; i < 4; ++i) a[i] = xs[bb * 4 + i][kk];
#pragma unroll
      for (int j = 0; j < 4; ++j) w4[j] = Ws[vb + 16 * j][kk];
#pragma unroll
      for (int i = 0; i < 4; ++i)
#pragma unroll
        for (int j = 0; j < 4; ++j) acc[i][j] += a[i] * w4[j];
    }
    __syncthreads();
  }
  float* dst = ghh ? (half ? gh1 : gh0) : (half ? gi1 : gi0);
  const float* bias = ghh ? bhh : bih;
#pragma unroll
  for (int i = 0; i < 4; ++i)
#pragma unroll
    for (int j = 0; j < 4; ++j) {
      int g = gbase + vb + 16 * j;
      float v = acc[i][j] + (half ? 0.f : bias[g]);
      dst[(size_t)(bb * 4 + i) * G3_ + g] = v;
    }
}

// ---------------- GRU gates -> new_hidden (f32 + bf16 copy) ----------------
__global__ void k_gate(const float* __restrict__ gi0, const float* __restrict__ gi1,
                       const float* __restrict__ gh0, const float* __restrict__ gh1,
                       const float* __restrict__ hidden, float* __restrict__ newh,
                       unsigned short* __restrict__ newhbf) {
  int o = blockIdx.x * 256 + threadIdx.x;
  int b = o >> 10, h = o & 1023;
  size_t base = (size_t)b * G3_;
  float ir = gi0[base + h] + gi1[base + h];
  float iz = gi0[base + 1024 + h] + gi1[base + 1024 + h];
  float in = gi0[base + 2048 + h] + gi1[base + 2048 + h];
  float hr = gh0[base + h] + gh1[base + h];
  float hz = gh0[base + 1024 + h] + gh1[base + 1024 + h];
  float hn = gh0[base + 2048 + h] + gh1[base + 2048 + h];
  float r = 1.f / (1.f + expf(-(ir + hr)));
  float z = 1.f / (1.f + expf(-(iz + hz)));
  float n = tanhf(in + r * hn);
  float nh = (1.f - z) * n + z * hidden[o];
  newh[o] = nh;
  newhbf[o] = f2bf(nh);
}

// ---------------- output projection: bf16 MFMA, 64x128 tile ----------------
__global__ __launch_bounds__(256) void k_outproj_mfma(const unsigned short* __restrict__ newhbf,
                                                      const float* __restrict__ ow,
                                                      const float* __restrict__ ob,
                                                      float* __restrict__ pred) {
  __shared__ unsigned short As[2048];   // 4 KB
  __shared__ unsigned short Bs[4096];   // 8 KB
  const int t = threadIdx.x;
  const int w = t >> 6, l = t & 63;
  const int l15 = l & 15, l4 = l >> 4;
  const int vbase = blockIdx.x * 128;   // 250 blocks

  const unsigned short* aSrc = newhbf + (size_t)(t & 63) * H_ + (t >> 6) * 8;
  const int br = t >> 1, bh = t & 1;
  const float* bSrc = ow + (size_t)(vbase + br) * H_ + bh * 16;

  f32x4 acc[4][2] = {};

  for (int kc = 0; kc < H_; kc += 32) {
    async16(aSrc + kc, (char*)As + (size_t)t * 16);
    f32x4 v0 = *(const f32x4*)(bSrc + kc);
    f32x4 v1 = *(const f32x4*)(bSrc + kc + 4);
    f32x4 v2 = *(const f32x4*)(bSrc + kc + 8);
    f32x4 v3 = *(const f32x4*)(bSrc + kc + 12);
    ushort4 p0 = { f2bf(v0.x), f2bf(v0.y), f2bf(v0.z), f2bf(v0.w) };
    ushort4 p1 = { f2bf(v1.x), f2bf(v1.y), f2bf(v1.z), f2bf(v1.w) };
    ushort4 p2 = { f2bf(v2.x), f2bf(v2.y), f2bf(v2.z), f2bf(v2.w) };
    ushort4 p3 = { f2bf(v3.x), f2bf(v3.y), f2bf(v3.z), f2bf(v3.w) };
    const int kg0 = bh * 2;
    *(ushort4*)(Bs + kg0 * 1024 + br * 8)       = p0;
    *(ushort4*)(Bs + kg0 * 1024 + br * 8 + 4)   = p1;
    *(ushort4*)(Bs + (kg0 + 1) * 1024 + br * 8)     = p2;
    *(ushort4*)(Bs + (kg0 + 1) * 1024 + br * 8 + 4) = p3;
    __syncthreads();
    short8 af[4], bf[2];
#pragma unroll
    for (int rf = 0; rf < 4; ++rf)
      af[rf] = *(const short8*)(As + l4 * 512 + (rf * 16 + l15) * 8);
#pragma unroll
    for (int cf = 0; cf < 2; ++cf)
      bf[cf] = *(const short8*)(Bs + l4 * 1024 + (w * 32 + cf * 16 + l15) * 8);
#pragma unroll
    for (int rf = 0; rf < 4; ++rf)
#pragma unroll
      for (int cf = 0; cf < 2; ++cf)
        acc[rf][cf] = __builtin_amdgcn_mfma_f32_16x16x32_bf16(af[rf], bf[cf], acc[rf][cf], 0, 0, 0);
    __syncthreads();
  }

#pragma unroll
  for (int cf = 0; cf < 2; ++cf) {
    int col = vbase + w * 32 + cf * 16 + l15;
    float bias = ob[col];
#pragma unroll
    for (int rf = 0; rf < 4; ++rf)
#pragma unroll
      for (int j = 0; j < 4; ++j) {
        int row = rf * 16 + l4 * 4 + j;
        pred[(size_t)row * V_ + col] = acc[rf][cf][j] + bias;
      }
  }
}

extern "C" void kernel_launch(void* const* d_in, const int* in_sizes, int n_in,
                              void* d_out, int out_size, void* d_ws, size_t ws_size,
                              hipStream_t stream) {
  const int*   word   = (const int*)d_in[0];
  const float* hidden = (const float*)d_in[1];
  const float* enc    = (const float*)d_in[2];
  const float* emb    = (const float*)d_in[5];
  const float* lin1w  = (const float*)d_in[6];
  const float* lin1b  = (const float*)d_in[7];
  const float* lin2w  = (const float*)d_in[8];
  const float* lin2b  = (const float*)d_in[9];
  const float* vw     = (const float*)d_in[10];
  const float* Wih    = (const float*)d_in[12];
  const float* bih    = (const float*)d_in[13];
  const float* Whh    = (const float*)d_in[14];
  const float* bhh    = (const float*)d_in[15];
  const float* ow     = (const float*)d_in[16];
  const float* ob     = (const float*)d_in[17];

  float* out   = (float*)d_out;
  float* pred  = out;                   // [64][32000]
  float* newh  = out + 2048000;         // [64][1024]
  float* score = out + 2113536;         // [64][512]

  const size_t ENCBF = 134217728;       // 32768*2048*2
  const bool fast = ws_size >= ENCBF + 13107200;
  char* ws = (char*)d_ws;
  unsigned short* encbf = (unsigned short*)ws;      // fast path only
  size_t base = fast ? ENCBF : 0;
  unsigned short* bw = (unsigned short*)(ws + base);        // 4,194,304
  float* hx    = (float*)(ws + base + 4194304);             // 262,144
  float* wvbuf = (float*)(ws + base + 4456448);             // 131,072
  float* epart = (float*)(ws + base + 4587520);             // 2,097,152
  float* cpart = (float*)(ws + base + 6684672);             // 4,194,304
  float* ctx   = (float*)(ws + base + 10878976);            // 524,288
  float* gi0   = (float*)(ws + base + 11403264);            // 786,432
  float* gh0   = (float*)(ws + base + 12189696);            // 786,432
  unsigned short* nhbf = (unsigned short*)(ws + base + 12976128);  // 131,072
  // gi1/gh1 reuse the dead epart region (epart consumed by k_softmax before
  // k_grugemm runs; stream-serialized)
  float* gi1   = epart;                                     // 786,432
  float* gh1   = epart + 196608;                            // 786,432

  k_hx<<<16, 256, 0, stream>>>(hidden, lin1w, lin1b, lin2b, hx);
  if (fast) {
    k_conv<<<4096, 256, 0, stream>>>(enc, encbf, lin2w, bw, word, emb, wvbuf);
    k_attn_bf<<<2048, 256, 0, stream>>>(encbf, bw, hx, vw, epart);
    k_softmax<<<64, 256, 0, stream>>>(epart, score);
    k_ctxb<<<512, 256, 0, stream>>>(encbf, score, cpart);
  } else {
    k_conv<<<4096, 256, 0, stream>>>(enc, encbf, lin2w, bw, word, emb, wvbuf); // enc part unused
    k_attn<<<2048, 256, 0, stream>>>(enc, bw, hx, vw, epart);
    k_softmax<<<64, 256, 0, stream>>>(epart, score);
    k_ctx<<<1024, 256, 0, stream>>>(enc, score, cpart);
  }
  k_ctxred<<<128, 256, 0, stream>>>(cpart, ctx);
  k_grugemm<<<192, 256, 0, stream>>>(ctx, wvbuf, hidden, Wih, bih, Whh, bhh, gi0, gi1, gh0, gh1);
  k_gate<<<256, 256, 0, stream>>>(gi0, gi1, gh0, gh1, hidden, newh, nhbf);
  k_outproj_mfma<<<250, 256, 0, stream>>>(nhbf, ow, ob, pred);
}

// Round 8
// 463.087 us; speedup vs baseline: 1.3479x; 1.0871x over previous
//
#include <hip/hip_runtime.h>
#include <hip/hip_bf16.h>
#include <stdint.h>

typedef __attribute__((ext_vector_type(4))) float f32x4;
typedef __attribute__((ext_vector_type(8))) short short8;

#define B_   64
#define S_   512
#define H_   1024
#define E_   512
#define V_   32000
#define M_   2048            // D*H
#define BS_  32768           // B*S
#define XIN_ 2560            // M_+E_
#define G3_  3072

__device__ __forceinline__ unsigned short f2bf(float f) {
  union { float f; unsigned u; } x; x.f = f;
  unsigned r = x.u + 0x7fffu + ((x.u >> 16) & 1u);
  return (unsigned short)(r >> 16);
}

__device__ __forceinline__ float bf2f(unsigned short u) {
  union { unsigned u; float f; } x; x.u = (unsigned)u << 16; return x.f;
}

__device__ __forceinline__ void async16(const void* g, void* l) {
  __builtin_amdgcn_global_load_lds((const __attribute__((address_space(1))) unsigned*)g,
                                   (__attribute__((address_space(3))) unsigned*)l,
                                   16, 0, 0);
}

// ------- merged converter: enc->bf16 (16B stores), lin2_w->bf16, emb gather --
__global__ __launch_bounds__(256) void k_conv(const float* __restrict__ enc,
                                              unsigned short* __restrict__ ebf,
                                              const float* __restrict__ lin2w,
                                              unsigned short* __restrict__ bw,
                                              const int* __restrict__ word,
                                              const float* __restrict__ emb,
                                              float* __restrict__ wv) {
  const size_t NENC8 = (size_t)BS_ * M_ / 8;   // 8,388,608
  const size_t NW8   = (size_t)H_ * M_ / 8;    // 262,144
  const size_t NWV4  = (size_t)B_ * E_ / 4;    // 8,192
  const size_t total = NENC8 + NW8 + NWV4;
  for (size_t idx = (size_t)blockIdx.x * 256 + threadIdx.x; idx < total;
       idx += (size_t)gridDim.x * 256) {
    if (idx < NENC8) {
      f32x4 a = *(const f32x4*)(enc + idx * 8);
      f32x4 b = *(const f32x4*)(enc + idx * 8 + 4);
      short8 o = { (short)f2bf(a.x), (short)f2bf(a.y), (short)f2bf(a.z), (short)f2bf(a.w),
                   (short)f2bf(b.x), (short)f2bf(b.y), (short)f2bf(b.z), (short)f2bf(b.w) };
      *(short8*)(ebf + idx * 8) = o;
    } else if (idx < NENC8 + NW8) {
      size_t i = idx - NENC8;
      f32x4 a = *(const f32x4*)(lin2w + i * 8);
      f32x4 b = *(const f32x4*)(lin2w + i * 8 + 4);
      short8 o = { (short)f2bf(a.x), (short)f2bf(a.y), (short)f2bf(a.z), (short)f2bf(a.w),
                   (short)f2bf(b.x), (short)f2bf(b.y), (short)f2bf(b.z), (short)f2bf(b.w) };
      *(short8*)(bw + i * 8) = o;
    } else {
      size_t i = idx - NENC8 - NW8;     // < 8192
      int i0 = (int)i * 4;
      int b = i0 >> 9, c = i0 & 511;
      f32x4 v = *(const f32x4*)(emb + (size_t)word[b] * E_ + c);
      *(f32x4*)(wv + i0) = v;
    }
  }
}

// ---------------- h_x = hidden @ lin1_w.T + b1 + b2 (LDS-tiled 64x64) -------
__global__ __launch_bounds__(256) void k_hx(const float* __restrict__ hidden,
                                            const float* __restrict__ w1,
                                            const float* __restrict__ b1,
                                            const float* __restrict__ b2,
                                            float* __restrict__ hx) {
  __shared__ float hs[64][36];
  __shared__ float Ws[64][36];
  const int t = threadIdx.x;
  const int hbase = blockIdx.x * 64;     // 16 blocks
  const int hb = t & 15, bb = t >> 4;
  const int srow = t >> 2, sc0 = (t & 3) * 8;
  float acc[4][4] = {};
  for (int kc = 0; kc < H_; kc += 32) {
    *(f32x4*)&hs[srow][sc0]     = *(const f32x4*)(hidden + (size_t)srow * H_ + kc + sc0);
    *(f32x4*)&hs[srow][sc0 + 4] = *(const f32x4*)(hidden + (size_t)srow * H_ + kc + sc0 + 4);
    *(f32x4*)&Ws[srow][sc0]     = *(const f32x4*)(w1 + (size_t)(hbase + srow) * H_ + kc + sc0);
    *(f32x4*)&Ws[srow][sc0 + 4] = *(const f32x4*)(w1 + (size_t)(hbase + srow) * H_ + kc + sc0 + 4);
    __syncthreads();
#pragma unroll
    for (int kk = 0; kk < 32; ++kk) {
      float a[4], w4[4];
#pragma unroll
      for (int i = 0; i < 4; ++i) a[i] = hs[bb * 4 + i][kk];
#pragma unroll
      for (int j = 0; j < 4; ++j) w4[j] = Ws[hb + 16 * j][kk];
#pragma unroll
      for (int i = 0; i < 4; ++i)
#pragma unroll
        for (int j = 0; j < 4; ++j) acc[i][j] += a[i] * w4[j];
    }
    __syncthreads();
  }
#pragma unroll
  for (int i = 0; i < 4; ++i)
#pragma unroll
    for (int j = 0; j < 4; ++j) {
      int h = hbase + hb + 16 * j;
      hx[(size_t)(bb * 4 + i) * H_ + h] = acc[i][j] + b1[h] + b2[h];
    }
}

// ---------------- attention GEMM: 256x128 tile, 8 waves, depth-2 pipeline ----
// Staged bytes/FLOP -20% vs 128^2. 3-buf counted vmcnt(3); chunk-xor swizzle
// (conflicts=0, verified r6/r7); bn-inner XCD map; setprio around MFMA.
__global__ __launch_bounds__(512, 4) void k_attn2(const unsigned short* __restrict__ encbf,
                                                  const unsigned short* __restrict__ bw,
                                                  const float* __restrict__ hx,
                                                  const float* __restrict__ vw,
                                                  float* __restrict__ epart) {
  extern __shared__ char smem[];   // 3 * 24576 = 73728 B; per buf: A 16KB | B 8KB
  const int t = threadIdx.x;
  const int w8 = t >> 6, l = t & 63;
  const int wm = w8 >> 1, wn = w8 & 1;
  const int l15 = l & 15, l4 = l >> 4;
  const int bid = blockIdx.x;              // 1024
  const int xcd = bid & 7, idx = bid >> 3; // idx 0..127
  const int bm = xcd * 16 + (idx >> 3);    // XCD x owns bm x*16..x*16+15
  const int bn = idx & 7;                  // bn-inner: A-panel reuse on-XCD
  const int b = bm >> 1;                   // batch row (256-row tile in 512-row batch)

  f32x4 acc[4][4] = {};

  const unsigned short* Ag = encbf + (size_t)(bm * 256) * M_;
  const unsigned short* Bg = bw + (size_t)(bn * 128) * M_;

  // staging: 4 lanes per row, 64B/row footprint, chunks xor-permuted in-row
  const int lr = l >> 2, lc = l & 3;
  const int sw = (lr >> 1) & 3;            // row bits 1-2 (rows = base16 + lr)
  const unsigned short* aSrc0 = Ag + (size_t)(w8 * 32 + lr) * M_ + (lc ^ sw) * 8;
  const unsigned short* aSrc1 = aSrc0 + (size_t)16 * M_;
  const unsigned short* bSrc  = Bg + (size_t)(w8 * 16 + lr) * M_ + (lc ^ sw) * 8;
  // LDS read: slot xor matches write permutation
  const int slotoff = (l4 ^ ((l15 >> 1) & 3)) * 16;

#define STAGE(buf, kt) do { const int k0 = (kt) * 32;                       \
    char* base_ = smem + (buf) * 24576;                                     \
    async16(aSrc0 + k0, base_ + w8 * 2048 + l * 16);                        \
    async16(aSrc1 + k0, base_ + w8 * 2048 + 1024 + l * 16);                 \
    async16(bSrc  + k0, base_ + 16384 + w8 * 1024 + l * 16); } while (0)

  STAGE(0, 0);
  STAGE(1, 1);
  asm volatile("s_waitcnt vmcnt(3)" ::: "memory");   // stage(0) landed
  __builtin_amdgcn_s_barrier();

  int cur = 0;
  for (int kt = 0; kt < 64; ++kt) {
    int nx2 = cur + 2; if (nx2 >= 3) nx2 -= 3;
    if (kt < 62) STAGE(nx2, kt + 2);
    const char* aBase = smem + cur * 24576;
    const char* bBase = aBase + 16384;
    short8 af[4], bf[4];
#pragma unroll
    for (int m = 0; m < 4; ++m)
      af[m] = *(const short8*)(aBase + (wm * 64 + m * 16 + l15) * 64 + slotoff);
#pragma unroll
    for (int n = 0; n < 4; ++n)
      bf[n] = *(const short8*)(bBase + (wn * 64 + n * 16 + l15) * 64 + slotoff);
    __builtin_amdgcn_s_setprio(1);
#pragma unroll
    for (int m = 0; m < 4; ++m)
#pragma unroll
      for (int n = 0; n < 4; ++n)
        acc[m][n] = __builtin_amdgcn_mfma_f32_16x16x32_bf16(af[m], bf[n], acc[m][n], 0, 0, 0);
    __builtin_amdgcn_s_setprio(0);
    if (kt < 62) {
      asm volatile("s_waitcnt vmcnt(3)" ::: "memory");  // stage(kt+1) landed
    } else {
      asm volatile("s_waitcnt vmcnt(0)" ::: "memory");  // drain tail
    }
    __builtin_amdgcn_s_barrier();
    cur = cur + 1; if (cur >= 3) cur = 0;
  }
#undef STAGE

  // epilogue: e-partial = sum over this wave's 64 cols of v*tanh(hx + C)
  const int rbase = bm * 256 + wm * 64;
  const int colbase = bn * 128 + wn * 64;
  const int part = bn * 2 + wn;
#pragma unroll
  for (int m = 0; m < 4; ++m) {
#pragma unroll
    for (int j = 0; j < 4; ++j) {
      int rg = rbase + m * 16 + l4 * 4 + j;
      float sum = 0.f;
#pragma unroll
      for (int n = 0; n < 4; ++n) {
        int h = colbase + n * 16 + l15;
        sum += vw[h] * tanhf(hx[b * H_ + h] + acc[m][n][j]);
      }
      sum += __shfl_xor(sum, 1);
      sum += __shfl_xor(sum, 2);
      sum += __shfl_xor(sum, 4);
      sum += __shfl_xor(sum, 8);
      if (l15 == 0) epart[(size_t)part * BS_ + rg] = sum;
    }
  }
}

// ---------------- attention GEMM (128^2 static-LDS fallback, r7) ------------
__global__ __launch_bounds__(256) void k_attn_bf(const unsigned short* __restrict__ encbf,
                                                 const unsigned short* __restrict__ bw,
                                                 const float* __restrict__ hx,
                                                 const float* __restrict__ vw,
                                                 float* __restrict__ epart) {
  __shared__ unsigned short As[3][4096];
  __shared__ unsigned short Bs[3][4096];
  const int bid = blockIdx.x;              // 2048
  const int xcd = bid & 7, idx = bid >> 3;
  const int bm = xcd * 32 + (idx >> 3);
  const int bn = idx & 7;
  const int t = threadIdx.x;
  const int l = t & 63, w = t >> 6;
  const int wr = w >> 1, wc = w & 1;
  const int l15 = l & 15, l4 = l >> 4;

  f32x4 acc[4][4] = {};

  const unsigned short* Ag = encbf + (size_t)(bm * 128) * M_;
  const unsigned short* Bg = bw + (size_t)(bn * 128) * M_;

  const int srow = t >> 2;
  const int sc = ((t & 3) ^ ((t >> 3) & 3)) * 8;
  const unsigned short* ApT = Ag + (size_t)srow * M_ + sc;
  const unsigned short* BpT = Bg + (size_t)srow * M_ + sc;
  const int xoff = (l4 ^ ((l15 >> 1) & 3)) * 8;

#define STAGE(buf, kt) do { const int k0 = (kt) * 32;                    \
    async16(ApT + k0,             &As[buf][0]    + (size_t)t * 8);       \
    async16(ApT + 64 * M_ + k0,   &As[buf][2048] + (size_t)t * 8);       \
    async16(BpT + k0,             &Bs[buf][0]    + (size_t)t * 8);       \
    async16(BpT + 64 * M_ + k0,   &Bs[buf][2048] + (size_t)t * 8); } while (0)

  STAGE(0, 0);
  STAGE(1, 1);
  asm volatile("s_waitcnt vmcnt(4)" ::: "memory");
  __builtin_amdgcn_s_barrier();

  int cur = 0;
  for (int kt = 0; kt < 64; ++kt) {
    int nx2 = cur + 2; if (nx2 >= 3) nx2 -= 3;
    if (kt < 62) STAGE(nx2, kt + 2);
    short8 af[4], bf[4];
#pragma unroll
    for (int m = 0; m < 4; ++m)
      af[m] = *(const short8*)(&As[cur][(wr * 64 + m * 16 + l15) * 32 + xoff]);
#pragma unroll
    for (int n = 0; n < 4; ++n)
      bf[n] = *(const short8*)(&Bs[cur][(wc * 64 + n * 16 + l15) * 32 + xoff]);
#pragma unroll
    for (int m = 0; m < 4; ++m)
#pragma unroll
      for (int n = 0; n < 4; ++n)
        acc[m][n] = __builtin_amdgcn_mfma_f32_16x16x32_bf16(af[m], bf[n], acc[m][n], 0, 0, 0);
    if (kt < 62) {
      asm volatile("s_waitcnt vmcnt(4)" ::: "memory");
    } else {
      asm volatile("s_waitcnt vmcnt(0)" ::: "memory");
    }
    __builtin_amdgcn_s_barrier();
    cur = cur + 1; if (cur >= 3) cur = 0;
  }
#undef STAGE

  const int colbase = bn * 128 + wc * 64;
#pragma unroll
  for (int m = 0; m < 4; ++m) {
#pragma unroll
    for (int j = 0; j < 4; ++j) {
      int rloc = wr * 64 + m * 16 + l4 * 4 + j;
      int rg = bm * 128 + rloc;
      int b = rg >> 9;
      float sum = 0.f;
#pragma unroll
      for (int n = 0; n < 4; ++n) {
        int h = colbase + n * 16 + l15;
        sum += vw[h] * tanhf(hx[b * H_ + h] + acc[m][n][j]);
      }
      sum += __shfl_xor(sum, 1);
      sum += __shfl_xor(sum, 2);
      sum += __shfl_xor(sum, 4);
      sum += __shfl_xor(sum, 8);
      if (l15 == 0) epart[(size_t)(bn * 2 + wc) * BS_ + rg] = sum;
    }
  }
}

// ---------------- attention GEMM (slow fallback: fused f32 A conversion) ----
__global__ __launch_bounds__(256) void k_attn(const float* __restrict__ enc,
                                              const unsigned short* __restrict__ bw,
                                              const float* __restrict__ hx,
                                              const float* __restrict__ vw,
                                              float* __restrict__ epart) {
  __shared__ unsigned short As[128 * 32];
  __shared__ unsigned short Bs[128 * 32];
  const int bid = blockIdx.x;
  const int bm = bid & 255, bn = bid >> 8;
  const int t = threadIdx.x;
  const int l = t & 63, w = t >> 6;
  const int wr = w >> 1, wc = w & 1;
  const int l15 = l & 15, l4 = l >> 4;

  f32x4 acc[4][4] = {};

  const float* Ag = enc + (size_t)(bm * 128) * M_;
  const unsigned short* Bg = bw + (size_t)(bn * 128) * M_;

  const int ar = t >> 3;
  const int ac = (t & 7) * 4;
  const int br = t >> 2;
  const int bc = (t & 3) * 8;

  for (int kt = 0; kt < 64; ++kt) {
    const int k0 = kt * 32;
    async16(Bg + (size_t)br * M_ + k0 + bc, (char*)Bs + (size_t)t * 16);
    async16(Bg + (size_t)(br + 64) * M_ + k0 + bc, (char*)Bs + 4096 + (size_t)t * 16);
#pragma unroll
    for (int j = 0; j < 4; ++j) {
      f32x4 v = *(const f32x4*)(Ag + (size_t)(ar + j * 32) * M_ + k0 + ac);
      ushort4 o = { f2bf(v.x), f2bf(v.y), f2bf(v.z), f2bf(v.w) };
      *(ushort4*)(As + (ar + j * 32) * 32 + ac) = o;
    }
    __syncthreads();
    short8 af[4], bf[4];
#pragma unroll
    for (int m = 0; m < 4; ++m)
      af[m] = *(const short8*)(As + (wr * 64 + m * 16 + l15) * 32 + l4 * 8);
#pragma unroll
    for (int n = 0; n < 4; ++n)
      bf[n] = *(const short8*)(Bs + (wc * 64 + n * 16 + l15) * 32 + l4 * 8);
#pragma unroll
    for (int m = 0; m < 4; ++m)
#pragma unroll
      for (int n = 0; n < 4; ++n)
        acc[m][n] = __builtin_amdgcn_mfma_f32_16x16x32_bf16(af[m], bf[n], acc[m][n], 0, 0, 0);
    __syncthreads();
  }

  const int colbase = bn * 128 + wc * 64;
#pragma unroll
  for (int m = 0; m < 4; ++m) {
#pragma unroll
    for (int j = 0; j < 4; ++j) {
      int rloc = wr * 64 + m * 16 + l4 * 4 + j;
      int rg = bm * 128 + rloc;
      int b = rg >> 9;
      float sum = 0.f;
#pragma unroll
      for (int n = 0; n < 4; ++n) {
        int h = colbase + n * 16 + l15;
        sum += vw[h] * tanhf(hx[b * H_ + h] + acc[m][n][j]);
      }
      sum += __shfl_xor(sum, 1);
      sum += __shfl_xor(sum, 2);
      sum += __shfl_xor(sum, 4);
      sum += __shfl_xor(sum, 8);
      if (l15 == 0) epart[(size_t)(bn * 2 + wc) * BS_ + rg] = sum;
    }
  }
}

// ---------------- softmax over S per batch row (reduces 16 e-partials) ------
__global__ __launch_bounds__(256) void k_softmax(const float* __restrict__ epart,
                                                 float* __restrict__ score) {
  int b = blockIdx.x, t = threadIdx.x;
  float v0 = 0.f, v1 = 0.f;
#pragma unroll
  for (int p = 0; p < 16; ++p) {
    v0 += epart[(size_t)p * BS_ + b * S_ + t];
    v1 += epart[(size_t)p * BS_ + b * S_ + 256 + t];
  }
  int w = t >> 6, l = t & 63;
  float m = fmaxf(v0, v1);
#pragma unroll
  for (int off = 32; off; off >>= 1) m = fmaxf(m, __shfl_xor(m, off));
  __shared__ float sm[4];
  __shared__ float ssum[4];
  if (l == 0) sm[w] = m;
  __syncthreads();
  float M = fmaxf(fmaxf(sm[0], sm[1]), fmaxf(sm[2], sm[3]));
  float p0 = expf(v0 - M), p1 = expf(v1 - M);
  float s = p0 + p1;
#pragma unroll
  for (int off = 32; off; off >>= 1) s += __shfl_xor(s, off);
  if (l == 0) ssum[w] = s;
  __syncthreads();
  float inv = 1.f / (ssum[0] + ssum[1] + ssum[2] + ssum[3]);
  score[b * S_ + t] = p0 * inv;
  score[b * S_ + 256 + t] = p1 * inv;
}

// ---------------- context partials (bf16 enc read) ----------------
__global__ __launch_bounds__(256) void k_ctxb(const unsigned short* __restrict__ encbf,
                                              const float* __restrict__ score,
                                              float* __restrict__ cpart) {
  int blk = blockIdx.x;            // 512 = b(64) x sc(8)
  int b = blk >> 3, sc = blk & 7;
  int t = threadIdx.x;
  int m = t * 8;
  f32x4 acc0 = {0.f, 0.f, 0.f, 0.f}, acc1 = {0.f, 0.f, 0.f, 0.f};
  const unsigned short* ep = encbf + (size_t)(b * S_ + sc * 64) * M_ + m;
  const float* sp = score + b * S_ + sc * 64;
#pragma unroll 4
  for (int s8 = 0; s8 < 64; ++s8) {
    float sv = sp[s8];
    short8 v = *(const short8*)(ep + (size_t)s8 * M_);
    acc0.x += bf2f((unsigned short)v[0]) * sv;
    acc0.y += bf2f((unsigned short)v[1]) * sv;
    acc0.z += bf2f((unsigned short)v[2]) * sv;
    acc0.w += bf2f((unsigned short)v[3]) * sv;
    acc1.x += bf2f((unsigned short)v[4]) * sv;
    acc1.y += bf2f((unsigned short)v[5]) * sv;
    acc1.z += bf2f((unsigned short)v[6]) * sv;
    acc1.w += bf2f((unsigned short)v[7]) * sv;
  }
  float* dst = cpart + (size_t)sc * (B_ * M_) + b * M_ + m;
  *(f32x4*)dst = acc0;
  *(f32x4*)(dst + 4) = acc1;
}

// ---------------- context partials (f32 fallback) ----------------
__global__ __launch_bounds__(256) void k_ctx(const float* __restrict__ enc,
                                             const float* __restrict__ score,
                                             float* __restrict__ cpart) {
  int blk = blockIdx.x;
  int b = blk >> 4, mc = (blk >> 3) & 1, sc = blk & 7;
  int t = threadIdx.x;
  int m = mc * 1024 + t * 4;
  f32x4 acc = {0.f, 0.f, 0.f, 0.f};
  const float* ep = enc + (size_t)b * S_ * M_ + m;
  const float* sp = score + b * S_ + sc * 64;
#pragma unroll 4
  for (int s8 = 0; s8 < 64; ++s8) {
    float sv = sp[s8];
    f32x4 v = *(const f32x4*)(ep + (size_t)(sc * 64 + s8) * M_);
    acc += v * sv;
  }
  *(f32x4*)(cpart + (size_t)sc * (B_ * M_) + b * M_ + m) = acc;
}

__global__ void k_ctxred(const float* __restrict__ cpart, float* __restrict__ ctx) {
  int i0 = (blockIdx.x * 256 + threadIdx.x) * 4;
  f32x4 a = {0.f, 0.f, 0.f, 0.f};
#pragma unroll
  for (int p = 0; p < 8; ++p) a += *(const f32x4*)(cpart + (size_t)p * (B_ * M_) + i0);
  *(f32x4*)(ctx + i0) = a;
}

// ---------------- GRU GEMMs: 64x64 tile, 4x4/thread, K-split x2 -------------
__global__ __launch_bounds__(256) void k_grugemm(const float* __restrict__ ctx,
                                                 const float* __restrict__ wv,
                                                 const float* __restrict__ hidden,
                                                 const float* __restrict__ Wih,
                                                 const float* __restrict__ bih,
                                                 const float* __restrict__ Whh,
                                                 const float* __restrict__ bhh,
                                                 float* __restrict__ gi0,
                                                 float* __restrict__ gi1,
                                                 float* __restrict__ gh0,
                                                 float* __restrict__ gh1) {
  __shared__ float xs[64][36];
  __shared__ float Ws[64][36];
  const int t = threadIdx.x;
  const int blk = blockIdx.x;
  const bool ghh = blk >= 96;
  const int sub = ghh ? blk - 96 : blk;
  const int colt = sub % 48, half = sub / 48;
  const int gbase = colt * 64;
  const int K = ghh ? H_ : XIN_;
  const int klo = ghh ? (half ? 512 : 0) : (half ? 1280 : 0);
  const int khi = ghh ? (half ? 1024 : 512) : (half ? 2560 : 1280);
  const float* Wp = ghh ? Whh : Wih;
  const int vb = t & 15, bb = t >> 4;
  const int srow = t >> 2, sc0 = (t & 3) * 8;
  float acc[4][4] = {};
  for (int kc = klo; kc < khi; kc += 32) {
    f32x4 xa, xb;
    if (ghh) {
      xa = *(const f32x4*)(hidden + (size_t)srow * H_ + kc + sc0);
      xb = *(const f32x4*)(hidden + (size_t)srow * H_ + kc + sc0 + 4);
    } else if (kc + sc0 < M_) {
      xa = *(const f32x4*)(ctx + (size_t)srow * M_ + kc + sc0);
      xb = *(const f32x4*)(ctx + (size_t)srow * M_ + kc + sc0 + 4);
    } else {
      xa = *(const f32x4*)(wv + (size_t)srow * E_ + kc + sc0 - M_);
      xb = *(const f32x4*)(wv + (size_t)srow * E_ + kc + sc0 - M_ + 4);
    }
    *(f32x4*)&xs[srow][sc0] = xa;
    *(f32x4*)&xs[srow][sc0 + 4] = xb;
    *(f32x4*)&Ws[srow][sc0]     = *(const f32x4*)(Wp + (size_t)(gbase + srow) * K + kc + sc0);
    *(f32x4*)&Ws[srow][sc0 + 4] = *(const f32x4*)(Wp + (size_t)(gbase + srow) * K + kc + sc0 + 4);
    __syncthreads();
#pragma unroll
    for (int kk = 0; kk < 32; ++kk) {
      float a[4], w4[4];
#pragma unroll
      for (int i = 0; i < 4; ++i) a[i] = xs[bb * 4 + i][kk];
#pragma unroll
      for (int j = 0; j < 4; ++j) w4[j] = Ws[vb + 16 * j][kk];
#pragma unroll
      for (int i = 0; i < 4; ++i)
#pragma unroll
        for (int j = 0; j < 4; ++j) acc[i][j] += a[i] * w4[j];
    }
    __syncthreads();
  }
  float* dst = ghh ? (half ? gh1 : gh0) : (half ? gi1 : gi0);
  const float* bias = ghh ? bhh : bih;
#pragma unroll
  for (int i = 0; i < 4; ++i)
#pragma unroll
    for (int j = 0; j < 4; ++j) {
      int g = gbase + vb + 16 * j;
      float v = acc[i][j] + (half ? 0.f : bias[g]);
      dst[(size_t)(bb * 4 + i) * G3_ + g] = v;
    }
}

// ---------------- GRU gates -> new_hidden (f32 + bf16 copy) ----------------
__global__ void k_gate(const float* __restrict__ gi0, const float* __restrict__ gi1,
                       const float* __restrict__ gh0, const float* __restrict__ gh1,
                       const float* __restrict__ hidden, float* __restrict__ newh,
                       unsigned short* __restrict__ newhbf) {
  int o = blockIdx.x * 256 + threadIdx.x;
  int b = o >> 10, h = o & 1023;
  size_t base = (size_t)b * G3_;
  float ir = gi0[base + h] + gi1[base + h];
  float iz = gi0[base + 1024 + h] + gi1[base + 1024 + h];
  float in = gi0[base + 2048 + h] + gi1[base + 2048 + h];
  float hr = gh0[base + h] + gh1[base + h];
  float hz = gh0[base + 1024 + h] + gh1[base + 1024 + h];
  float hn = gh0[base + 2048 + h] + gh1[base + 2048 + h];
  float r = 1.f / (1.f + expf(-(ir + hr)));
  float z = 1.f / (1.f + expf(-(iz + hz)));
  float n = tanhf(in + r * hn);
  float nh = (1.f - z) * n + z * hidden[o];
  newh[o] = nh;
  newhbf[o] = f2bf(nh);
}

// ---------------- output projection: bf16 MFMA, 64x128 tile ----------------
__global__ __launch_bounds__(256) void k_outproj_mfma(const unsigned short* __restrict__ newhbf,
                                                      const float* __restrict__ ow,
                                                      const float* __restrict__ ob,
                                                      float* __restrict__ pred) {
  __shared__ unsigned short As[2048];   // 4 KB
  __shared__ unsigned short Bs[4096];   // 8 KB
  const int t = threadIdx.x;
  const int w = t >> 6, l = t & 63;
  const int l15 = l & 15, l4 = l >> 4;
  const int vbase = blockIdx.x * 128;   // 250 blocks

  const unsigned short* aSrc = newhbf + (size_t)(t & 63) * H_ + (t >> 6) * 8;
  const int br = t >> 1, bh = t & 1;
  const float* bSrc = ow + (size_t)(vbase + br) * H_ + bh * 16;

  f32x4 acc[4][2] = {};

  for (int kc = 0; kc < H_; kc += 32) {
    async16(aSrc + kc, (char*)As + (size_t)t * 16);
    f32x4 v0 = *(const f32x4*)(bSrc + kc);
    f32x4 v1 = *(const f32x4*)(bSrc + kc + 4);
    f32x4 v2 = *(const f32x4*)(bSrc + kc + 8);
    f32x4 v3 = *(const f32x4*)(bSrc + kc + 12);
    ushort4 p0 = { f2bf(v0.x), f2bf(v0.y), f2bf(v0.z), f2bf(v0.w) };
    ushort4 p1 = { f2bf(v1.x), f2bf(v1.y), f2bf(v1.z), f2bf(v1.w) };
    ushort4 p2 = { f2bf(v2.x), f2bf(v2.y), f2bf(v2.z), f2bf(v2.w) };
    ushort4 p3 = { f2bf(v3.x), f2bf(v3.y), f2bf(v3.z), f2bf(v3.w) };
    const int kg0 = bh * 2;
    *(ushort4*)(Bs + kg0 * 1024 + br * 8)       = p0;
    *(ushort4*)(Bs + kg0 * 1024 + br * 8 + 4)   = p1;
    *(ushort4*)(Bs + (kg0 + 1) * 1024 + br * 8)     = p2;
    *(ushort4*)(Bs + (kg0 + 1) * 1024 + br * 8 + 4) = p3;
    __syncthreads();
    short8 af[4], bf[2];
#pragma unroll
    for (int rf = 0; rf < 4; ++rf)
      af[rf] = *(const short8*)(As + l4 * 512 + (rf * 16 + l15) * 8);
#pragma unroll
    for (int cf = 0; cf < 2; ++cf)
      bf[cf] = *(const short8*)(Bs + l4 * 1024 + (w * 32 + cf * 16 + l15) * 8);
#pragma unroll
    for (int rf = 0; rf < 4; ++rf)
#pragma unroll
      for (int cf = 0; cf < 2; ++cf)
        acc[rf][cf] = __builtin_amdgcn_mfma_f32_16x16x32_bf16(af[rf], bf[cf], acc[rf][cf], 0, 0, 0);
    __syncthreads();
  }

#pragma unroll
  for (int cf = 0; cf < 2; ++cf) {
    int col = vbase + w * 32 + cf * 16 + l15;
    float bias = ob[col];
#pragma unroll
    for (int rf = 0; rf < 4; ++rf)
#pragma unroll
      for (int j = 0; j < 4; ++j) {
        int row = rf * 16 + l4 * 4 + j;
        pred[(size_t)row * V_ + col] = acc[rf][cf][j] + bias;
      }
  }
}

extern "C" void kernel_launch(void* const* d_in, const int* in_sizes, int n_in,
                              void* d_out, int out_size, void* d_ws, size_t ws_size,
                              hipStream_t stream) {
  const int*   word   = (const int*)d_in[0];
  const float* hidden = (const float*)d_in[1];
  const float* enc    = (const float*)d_in[2];
  const float* emb    = (const float*)d_in[5];
  const float* lin1w  = (const float*)d_in[6];
  const float* lin1b  = (const float*)d_in[7];
  const float* lin2w  = (const float*)d_in[8];
  const float* lin2b  = (const float*)d_in[9];
  const float* vw     = (const float*)d_in[10];
  const float* Wih    = (const float*)d_in[12];
  const float* bih    = (const float*)d_in[13];
  const float* Whh    = (const float*)d_in[14];
  const float* bhh    = (const float*)d_in[15];
  const float* ow     = (const float*)d_in[16];
  const float* ob     = (const float*)d_in[17];

  float* out   = (float*)d_out;
  float* pred  = out;                   // [64][32000]
  float* newh  = out + 2048000;         // [64][1024]
  float* score = out + 2113536;         // [64][512]

  const size_t ENCBF = 134217728;       // 32768*2048*2
  const bool fast = ws_size >= ENCBF + 13107200;
  char* ws = (char*)d_ws;
  unsigned short* encbf = (unsigned short*)ws;      // fast path only
  size_t base = fast ? ENCBF : 0;
  unsigned short* bw = (unsigned short*)(ws + base);        // 4,194,304
  float* hx    = (float*)(ws + base + 4194304);             // 262,144
  float* wvbuf = (float*)(ws + base + 4456448);             // 131,072
  float* epart = (float*)(ws + base + 4587520);             // 2,097,152
  float* cpart = (float*)(ws + base + 6684672);             // 4,194,304
  float* ctx   = (float*)(ws + base + 10878976);            // 524,288
  float* gi0   = (float*)(ws + base + 11403264);            // 786,432
  float* gh0   = (float*)(ws + base + 12189696);            // 786,432
  unsigned short* nhbf = (unsigned short*)(ws + base + 12976128);  // 131,072
  // gi1/gh1 reuse the dead epart region (epart consumed by k_softmax before
  // k_grugemm runs; stream-serialized)
  float* gi1   = epart;                                     // 786,432
  float* gh1   = epart + 196608;                            // 786,432

  bool use2 = false;
  if (fast) {
    hipError_t e = hipFuncSetAttribute((const void*)k_attn2,
        hipFuncAttributeMaxDynamicSharedMemorySize, 73728);
    use2 = (e == hipSuccess);
  }

  k_hx<<<16, 256, 0, stream>>>(hidden, lin1w, lin1b, lin2b, hx);
  if (fast) {
    k_conv<<<4096, 256, 0, stream>>>(enc, encbf, lin2w, bw, word, emb, wvbuf);
    if (use2) {
      k_attn2<<<1024, 512, 73728, stream>>>(encbf, bw, hx, vw, epart);
    } else {
      k_attn_bf<<<2048, 256, 0, stream>>>(encbf, bw, hx, vw, epart);
    }
    k_softmax<<<64, 256, 0, stream>>>(epart, score);
    k_ctxb<<<512, 256, 0, stream>>>(encbf, score, cpart);
  } else {
    k_conv<<<4096, 256, 0, stream>>>(enc, encbf, lin2w, bw, word, emb, wvbuf); // enc part unused
    k_attn<<<2048, 256, 0, stream>>>(enc, bw, hx, vw, epart);
    k_softmax<<<64, 256, 0, stream>>>(epart, score);
    k_ctx<<<1024, 256, 0, stream>>>(enc, score, cpart);
  }
  k_ctxred<<<128, 256, 0, stream>>>(cpart, ctx);
  k_grugemm<<<192, 256, 0, stream>>>(ctx, wvbuf, hidden, Wih, bih, Whh, bhh, gi0, gi1, gh0, gh1);
  k_gate<<<256, 256, 0, stream>>>(gi0, gi1, gh0, gh1, hidden, newh, nhbf);
  k_outproj_mfma<<<250, 256, 0, stream>>>(nhbf, ow, ob, pred);
}

// Round 9
// 452.091 us; speedup vs baseline: 1.3807x; 1.0243x over previous
//
#include <hip/hip_runtime.h>
#include <hip/hip_bf16.h>
#include <stdint.h>

typedef __attribute__((ext_vector_type(4))) float f32x4;
typedef __attribute__((ext_vector_type(8))) short short8;

#define B_   64
#define S_   512
#define H_   1024
#define E_   512
#define V_   32000
#define M_   2048            // D*H
#define BS_  32768           // B*S
#define XIN_ 2560            // M_+E_
#define G3_  3072

__device__ __forceinline__ unsigned short f2bf(float f) {
  union { float f; unsigned u; } x; x.f = f;
  unsigned r = x.u + 0x7fffu + ((x.u >> 16) & 1u);
  return (unsigned short)(r >> 16);
}

__device__ __forceinline__ float bf2f(unsigned short u) {
  union { unsigned u; float f; } x; x.u = (unsigned)u << 16; return x.f;
}

__device__ __forceinline__ void async16(const void* g, void* l) {
  __builtin_amdgcn_global_load_lds((const __attribute__((address_space(1))) unsigned*)g,
                                   (__attribute__((address_space(3))) unsigned*)l,
                                   16, 0, 0);
}

// ------- merged: enc->bf16, lin2_w->bf16, emb gather, + h_x GEMM (blocks>=4096)
__global__ __launch_bounds__(256) void k_convhx(const float* __restrict__ enc,
                                                unsigned short* __restrict__ ebf,
                                                const float* __restrict__ lin2w,
                                                unsigned short* __restrict__ bw,
                                                const int* __restrict__ word,
                                                const float* __restrict__ emb,
                                                float* __restrict__ wv,
                                                const float* __restrict__ hidden,
                                                const float* __restrict__ w1,
                                                const float* __restrict__ b1,
                                                const float* __restrict__ b2,
                                                float* __restrict__ hx) {
  __shared__ float hs[64][36];
  __shared__ float Ws[64][36];
  const int t = threadIdx.x;
  if (blockIdx.x >= 4096) {
    // ---- h_x path: 16 blocks, 64x64 tile each ----
    const int hbase = (blockIdx.x - 4096) * 64;
    const int hb = t & 15, bb = t >> 4;
    const int srow = t >> 2, sc0 = (t & 3) * 8;
    float acc[4][4] = {};
    for (int kc = 0; kc < H_; kc += 32) {
      *(f32x4*)&hs[srow][sc0]     = *(const f32x4*)(hidden + (size_t)srow * H_ + kc + sc0);
      *(f32x4*)&hs[srow][sc0 + 4] = *(const f32x4*)(hidden + (size_t)srow * H_ + kc + sc0 + 4);
      *(f32x4*)&Ws[srow][sc0]     = *(const f32x4*)(w1 + (size_t)(hbase + srow) * H_ + kc + sc0);
      *(f32x4*)&Ws[srow][sc0 + 4] = *(const f32x4*)(w1 + (size_t)(hbase + srow) * H_ + kc + sc0 + 4);
      __syncthreads();
#pragma unroll
      for (int kk = 0; kk < 32; ++kk) {
        float a[4], w4[4];
#pragma unroll
        for (int i = 0; i < 4; ++i) a[i] = hs[bb * 4 + i][kk];
#pragma unroll
        for (int j = 0; j < 4; ++j) w4[j] = Ws[hb + 16 * j][kk];
#pragma unroll
        for (int i = 0; i < 4; ++i)
#pragma unroll
          for (int j = 0; j < 4; ++j) acc[i][j] += a[i] * w4[j];
      }
      __syncthreads();
    }
#pragma unroll
    for (int i = 0; i < 4; ++i)
#pragma unroll
      for (int j = 0; j < 4; ++j) {
        int h = hbase + hb + 16 * j;
        hx[(size_t)(bb * 4 + i) * H_ + h] = acc[i][j] + b1[h] + b2[h];
      }
    return;
  }
  // ---- converter path: grid-stride over 4096 blocks ----
  const size_t NENC8 = (size_t)BS_ * M_ / 8;   // 8,388,608
  const size_t NW8   = (size_t)H_ * M_ / 8;    // 262,144
  const size_t NWV4  = (size_t)B_ * E_ / 4;    // 8,192
  const size_t total = NENC8 + NW8 + NWV4;
  for (size_t idx = (size_t)blockIdx.x * 256 + t; idx < total;
       idx += (size_t)4096 * 256) {
    if (idx < NENC8) {
      f32x4 a = *(const f32x4*)(enc + idx * 8);
      f32x4 b = *(const f32x4*)(enc + idx * 8 + 4);
      short8 o = { (short)f2bf(a.x), (short)f2bf(a.y), (short)f2bf(a.z), (short)f2bf(a.w),
                   (short)f2bf(b.x), (short)f2bf(b.y), (short)f2bf(b.z), (short)f2bf(b.w) };
      *(short8*)(ebf + idx * 8) = o;
    } else if (idx < NENC8 + NW8) {
      size_t i = idx - NENC8;
      f32x4 a = *(const f32x4*)(lin2w + i * 8);
      f32x4 b = *(const f32x4*)(lin2w + i * 8 + 4);
      short8 o = { (short)f2bf(a.x), (short)f2bf(a.y), (short)f2bf(a.z), (short)f2bf(a.w),
                   (short)f2bf(b.x), (short)f2bf(b.y), (short)f2bf(b.z), (short)f2bf(b.w) };
      *(short8*)(bw + i * 8) = o;
    } else {
      size_t i = idx - NENC8 - NW8;     // < 8192
      int i0 = (int)i * 4;
      int b = i0 >> 9, c = i0 & 511;
      f32x4 v = *(const f32x4*)(emb + (size_t)word[b] * E_ + c);
      *(f32x4*)(wv + i0) = v;
    }
  }
}

// ---------------- attention GEMM: 256x256 tile, 8 waves (4Mx2N) -------------
// Staged bytes 1.05 GB (-33% vs 256x128). 3-buf depth-2, counted vmcnt(4),
// chunk-xor swizzle (conflicts=0), bn-inner XCD map, setprio. 96KB LDS.
__global__ __launch_bounds__(512, 2) void k_attn3(const unsigned short* __restrict__ encbf,
                                                  const unsigned short* __restrict__ bw,
                                                  const float* __restrict__ hx,
                                                  const float* __restrict__ vw,
                                                  float* __restrict__ epart) {
  extern __shared__ char smem[];   // 3 * 32768; per buf: A 16KB | B 16KB
  const int t = threadIdx.x;
  const int w8 = t >> 6, l = t & 63;
  const int wm = w8 >> 1, wn = w8 & 1;
  const int l15 = l & 15, l4 = l >> 4;
  const int bid = blockIdx.x;              // 512
  const int xcd = bid & 7, idx = bid >> 3; // idx 0..63
  const int bm = xcd * 16 + (idx >> 2);    // XCD x owns bm x*16..x*16+15
  const int bn = idx & 3;                  // bn-inner: A-panel reuse on-XCD
  const int b = bm >> 1;                   // batch row (256-row tile, 512-row batch)

  f32x4 acc[4][8] = {};

  const unsigned short* Ag = encbf + (size_t)(bm * 256) * M_;
  const unsigned short* Bg = bw + (size_t)(bn * 256) * M_;

  // staging: 4 lanes/row, 64B/row, chunks xor-permuted in-row (r8-verified)
  const int lr = l >> 2, lc = l & 3;
  const int sw = (lr >> 1) & 3;
  const unsigned short* aSrc0 = Ag + (size_t)(w8 * 32 + lr) * M_ + (lc ^ sw) * 8;
  const unsigned short* aSrc1 = aSrc0 + (size_t)16 * M_;
  const unsigned short* bSrc0 = Bg + (size_t)(w8 * 32 + lr) * M_ + (lc ^ sw) * 8;
  const unsigned short* bSrc1 = bSrc0 + (size_t)16 * M_;
  const int slotoff = (l4 ^ ((l15 >> 1) & 3)) * 16;

#define STAGE(buf, kt) do { const int k0 = (kt) * 32;                       \
    char* base_ = smem + (buf) * 32768;                                     \
    async16(aSrc0 + k0, base_ + w8 * 2048 + l * 16);                        \
    async16(aSrc1 + k0, base_ + w8 * 2048 + 1024 + l * 16);                 \
    async16(bSrc0 + k0, base_ + 16384 + w8 * 2048 + l * 16);                \
    async16(bSrc1 + k0, base_ + 16384 + w8 * 2048 + 1024 + l * 16); } while (0)

  STAGE(0, 0);
  STAGE(1, 1);
  asm volatile("s_waitcnt vmcnt(4)" ::: "memory");   // stage(0) landed
  __builtin_amdgcn_s_barrier();

  int cur = 0;
  for (int kt = 0; kt < 64; ++kt) {
    int nx2 = cur + 2; if (nx2 >= 3) nx2 -= 3;
    if (kt < 62) STAGE(nx2, kt + 2);
    const char* aBase = smem + cur * 32768;
    const char* bBase = aBase + 16384;
    short8 af[4], bf[8];
#pragma unroll
    for (int m = 0; m < 4; ++m)
      af[m] = *(const short8*)(aBase + (wm * 64 + m * 16 + l15) * 64 + slotoff);
#pragma unroll
    for (int n = 0; n < 8; ++n)
      bf[n] = *(const short8*)(bBase + (wn * 128 + n * 16 + l15) * 64 + slotoff);
    __builtin_amdgcn_s_setprio(1);
#pragma unroll
    for (int m = 0; m < 4; ++m)
#pragma unroll
      for (int n = 0; n < 8; ++n)
        acc[m][n] = __builtin_amdgcn_mfma_f32_16x16x32_bf16(af[m], bf[n], acc[m][n], 0, 0, 0);
    __builtin_amdgcn_s_setprio(0);
    if (kt < 62) {
      asm volatile("s_waitcnt vmcnt(4)" ::: "memory");  // stage(kt+1) landed
    } else {
      asm volatile("s_waitcnt vmcnt(0)" ::: "memory");  // drain tail
    }
    __builtin_amdgcn_s_barrier();
    cur = cur + 1; if (cur >= 3) cur = 0;
  }
#undef STAGE

  // epilogue: e-partial = sum over this wave's 128 cols of v*tanh(hx + C)
  const int rbase = bm * 256 + wm * 64;
  const int colbase = bn * 256 + wn * 128;
  const int part = bn * 2 + wn;            // 8 partials
#pragma unroll
  for (int m = 0; m < 4; ++m) {
#pragma unroll
    for (int j = 0; j < 4; ++j) {
      int rg = rbase + m * 16 + l4 * 4 + j;
      float sum = 0.f;
#pragma unroll
      for (int n = 0; n < 8; ++n) {
        int h = colbase + n * 16 + l15;
        sum += vw[h] * tanhf(hx[b * H_ + h] + acc[m][n][j]);
      }
      sum += __shfl_xor(sum, 1);
      sum += __shfl_xor(sum, 2);
      sum += __shfl_xor(sum, 4);
      sum += __shfl_xor(sum, 8);
      if (l15 == 0) epart[(size_t)part * BS_ + rg] = sum;
    }
  }
}

// ---------------- attention GEMM: 256x128, 8 waves (r8, 16 partials) --------
__global__ __launch_bounds__(512, 4) void k_attn2(const unsigned short* __restrict__ encbf,
                                                  const unsigned short* __restrict__ bw,
                                                  const float* __restrict__ hx,
                                                  const float* __restrict__ vw,
                                                  float* __restrict__ epart) {
  extern __shared__ char smem[];   // 3 * 24576
  const int t = threadIdx.x;
  const int w8 = t >> 6, l = t & 63;
  const int wm = w8 >> 1, wn = w8 & 1;
  const int l15 = l & 15, l4 = l >> 4;
  const int bid = blockIdx.x;              // 1024
  const int xcd = bid & 7, idx = bid >> 3;
  const int bm = xcd * 16 + (idx >> 3);
  const int bn = idx & 7;
  const int b = bm >> 1;

  f32x4 acc[4][4] = {};

  const unsigned short* Ag = encbf + (size_t)(bm * 256) * M_;
  const unsigned short* Bg = bw + (size_t)(bn * 128) * M_;

  const int lr = l >> 2, lc = l & 3;
  const int sw = (lr >> 1) & 3;
  const unsigned short* aSrc0 = Ag + (size_t)(w8 * 32 + lr) * M_ + (lc ^ sw) * 8;
  const unsigned short* aSrc1 = aSrc0 + (size_t)16 * M_;
  const unsigned short* bSrc  = Bg + (size_t)(w8 * 16 + lr) * M_ + (lc ^ sw) * 8;
  const int slotoff = (l4 ^ ((l15 >> 1) & 3)) * 16;

#define STAGE(buf, kt) do { const int k0 = (kt) * 32;                       \
    char* base_ = smem + (buf) * 24576;                                     \
    async16(aSrc0 + k0, base_ + w8 * 2048 + l * 16);                        \
    async16(aSrc1 + k0, base_ + w8 * 2048 + 1024 + l * 16);                 \
    async16(bSrc  + k0, base_ + 16384 + w8 * 1024 + l * 16); } while (0)

  STAGE(0, 0);
  STAGE(1, 1);
  asm volatile("s_waitcnt vmcnt(3)" ::: "memory");
  __builtin_amdgcn_s_barrier();

  int cur = 0;
  for (int kt = 0; kt < 64; ++kt) {
    int nx2 = cur + 2; if (nx2 >= 3) nx2 -= 3;
    if (kt < 62) STAGE(nx2, kt + 2);
    const char* aBase = smem + cur * 24576;
    const char* bBase = aBase + 16384;
    short8 af[4], bf[4];
#pragma unroll
    for (int m = 0; m < 4; ++m)
      af[m] = *(const short8*)(aBase + (wm * 64 + m * 16 + l15) * 64 + slotoff);
#pragma unroll
    for (int n = 0; n < 4; ++n)
      bf[n] = *(const short8*)(bBase + (wn * 64 + n * 16 + l15) * 64 + slotoff);
    __builtin_amdgcn_s_setprio(1);
#pragma unroll
    for (int m = 0; m < 4; ++m)
#pragma unroll
      for (int n = 0; n < 4; ++n)
        acc[m][n] = __builtin_amdgcn_mfma_f32_16x16x32_bf16(af[m], bf[n], acc[m][n], 0, 0, 0);
    __builtin_amdgcn_s_setprio(0);
    if (kt < 62) {
      asm volatile("s_waitcnt vmcnt(3)" ::: "memory");
    } else {
      asm volatile("s_waitcnt vmcnt(0)" ::: "memory");
    }
    __builtin_amdgcn_s_barrier();
    cur = cur + 1; if (cur >= 3) cur = 0;
  }
#undef STAGE

  const int rbase = bm * 256 + wm * 64;
  const int colbase = bn * 128 + wn * 64;
  const int part = bn * 2 + wn;
#pragma unroll
  for (int m = 0; m < 4; ++m) {
#pragma unroll
    for (int j = 0; j < 4; ++j) {
      int rg = rbase + m * 16 + l4 * 4 + j;
      float sum = 0.f;
#pragma unroll
      for (int n = 0; n < 4; ++n) {
        int h = colbase + n * 16 + l15;
        sum += vw[h] * tanhf(hx[b * H_ + h] + acc[m][n][j]);
      }
      sum += __shfl_xor(sum, 1);
      sum += __shfl_xor(sum, 2);
      sum += __shfl_xor(sum, 4);
      sum += __shfl_xor(sum, 8);
      if (l15 == 0) epart[(size_t)part * BS_ + rg] = sum;
    }
  }
}

// ---------------- attention GEMM (slow fallback: fused f32 A conversion) ----
__global__ __launch_bounds__(256) void k_attn(const float* __restrict__ enc,
                                              const unsigned short* __restrict__ bw,
                                              const float* __restrict__ hx,
                                              const float* __restrict__ vw,
                                              float* __restrict__ epart) {
  __shared__ unsigned short As[128 * 32];
  __shared__ unsigned short Bs[128 * 32];
  const int bid = blockIdx.x;
  const int bm = bid & 255, bn = bid >> 8;
  const int t = threadIdx.x;
  const int l = t & 63, w = t >> 6;
  const int wr = w >> 1, wc = w & 1;
  const int l15 = l & 15, l4 = l >> 4;

  f32x4 acc[4][4] = {};

  const float* Ag = enc + (size_t)(bm * 128) * M_;
  const unsigned short* Bg = bw + (size_t)(bn * 128) * M_;

  const int ar = t >> 3;
  const int ac = (t & 7) * 4;
  const int br = t >> 2;
  const int bc = (t & 3) * 8;

  for (int kt = 0; kt < 64; ++kt) {
    const int k0 = kt * 32;
    async16(Bg + (size_t)br * M_ + k0 + bc, (char*)Bs + (size_t)t * 16);
    async16(Bg + (size_t)(br + 64) * M_ + k0 + bc, (char*)Bs + 4096 + (size_t)t * 16);
#pragma unroll
    for (int j = 0; j < 4; ++j) {
      f32x4 v = *(const f32x4*)(Ag + (size_t)(ar + j * 32) * M_ + k0 + ac);
      ushort4 o = { f2bf(v.x), f2bf(v.y), f2bf(v.z), f2bf(v.w) };
      *(ushort4*)(As + (ar + j * 32) * 32 + ac) = o;
    }
    __syncthreads();
    short8 af[4], bf[4];
#pragma unroll
    for (int m = 0; m < 4; ++m)
      af[m] = *(const short8*)(As + (wr * 64 + m * 16 + l15) * 32 + l4 * 8);
#pragma unroll
    for (int n = 0; n < 4; ++n)
      bf[n] = *(const short8*)(Bs + (wc * 64 + n * 16 + l15) * 32 + l4 * 8);
#pragma unroll
    for (int m = 0; m < 4; ++m)
#pragma unroll
      for (int n = 0; n < 4; ++n)
        acc[m][n] = __builtin_amdgcn_mfma_f32_16x16x32_bf16(af[m], bf[n], acc[m][n], 0, 0, 0);
    __syncthreads();
  }

  const int colbase = bn * 128 + wc * 64;
#pragma unroll
  for (int m = 0; m < 4; ++m) {
#pragma unroll
    for (int j = 0; j < 4; ++j) {
      int rloc = wr * 64 + m * 16 + l4 * 4 + j;
      int rg = bm * 128 + rloc;
      int b = rg >> 9;
      float sum = 0.f;
#pragma unroll
      for (int n = 0; n < 4; ++n) {
        int h = colbase + n * 16 + l15;
        sum += vw[h] * tanhf(hx[b * H_ + h] + acc[m][n][j]);
      }
      sum += __shfl_xor(sum, 1);
      sum += __shfl_xor(sum, 2);
      sum += __shfl_xor(sum, 4);
      sum += __shfl_xor(sum, 8);
      if (l15 == 0) epart[(size_t)(bn * 2 + wc) * BS_ + rg] = sum;
    }
  }
}

// ---------------- softmax over S per batch row (reduces npart partials) -----
__global__ __launch_bounds__(256) void k_softmax(const float* __restrict__ epart,
                                                 float* __restrict__ score,
                                                 int npart) {
  int b = blockIdx.x, t = threadIdx.x;
  float v0 = 0.f, v1 = 0.f;
  for (int p = 0; p < npart; ++p) {
    v0 += epart[(size_t)p * BS_ + b * S_ + t];
    v1 += epart[(size_t)p * BS_ + b * S_ + 256 + t];
  }
  int w = t >> 6, l = t & 63;
  float m = fmaxf(v0, v1);
#pragma unroll
  for (int off = 32; off; off >>= 1) m = fmaxf(m, __shfl_xor(m, off));
  __shared__ float sm[4];
  __shared__ float ssum[4];
  if (l == 0) sm[w] = m;
  __syncthreads();
  float M = fmaxf(fmaxf(sm[0], sm[1]), fmaxf(sm[2], sm[3]));
  float p0 = expf(v0 - M), p1 = expf(v1 - M);
  float s = p0 + p1;
#pragma unroll
  for (int off = 32; off; off >>= 1) s += __shfl_xor(s, off);
  if (l == 0) ssum[w] = s;
  __syncthreads();
  float inv = 1.f / (ssum[0] + ssum[1] + ssum[2] + ssum[3]);
  score[b * S_ + t] = p0 * inv;
  score[b * S_ + 256 + t] = p1 * inv;
}

// ---------------- context partials (bf16 enc read) ----------------
__global__ __launch_bounds__(256) void k_ctxb(const unsigned short* __restrict__ encbf,
                                              const float* __restrict__ score,
                                              float* __restrict__ cpart) {
  int blk = blockIdx.x;            // 512 = b(64) x sc(8)
  int b = blk >> 3, sc = blk & 7;
  int t = threadIdx.x;
  int m = t * 8;
  f32x4 acc0 = {0.f, 0.f, 0.f, 0.f}, acc1 = {0.f, 0.f, 0.f, 0.f};
  const unsigned short* ep = encbf + (size_t)(b * S_ + sc * 64) * M_ + m;
  const float* sp = score + b * S_ + sc * 64;
#pragma unroll 4
  for (int s8 = 0; s8 < 64; ++s8) {
    float sv = sp[s8];
    short8 v = *(const short8*)(ep + (size_t)s8 * M_);
    acc0.x += bf2f((unsigned short)v[0]) * sv;
    acc0.y += bf2f((unsigned short)v[1]) * sv;
    acc0.z += bf2f((unsigned short)v[2]) * sv;
    acc0.w += bf2f((unsigned short)v[3]) * sv;
    acc1.x += bf2f((unsigned short)v[4]) * sv;
    acc1.y += bf2f((unsigned short)v[5]) * sv;
    acc1.z += bf2f((unsigned short)v[6]) * sv;
    acc1.w += bf2f((unsigned short)v[7]) * sv;
  }
  float* dst = cpart + (size_t)sc * (B_ * M_) + b * M_ + m;
  *(f32x4*)dst = acc0;
  *(f32x4*)(dst + 4) = acc1;
}

// ---------------- context partials (f32 fallback) ----------------
__global__ __launch_bounds__(256) void k_ctx(const float* __restrict__ enc,
                                             const float* __restrict__ score,
                                             float* __restrict__ cpart) {
  int blk = blockIdx.x;
  int b = blk >> 4, mc = (blk >> 3) & 1, sc = blk & 7;
  int t = threadIdx.x;
  int m = mc * 1024 + t * 4;
  f32x4 acc = {0.f, 0.f, 0.f, 0.f};
  const float* ep = enc + (size_t)b * S_ * M_ + m;
  const float* sp = score + b * S_ + sc * 64;
#pragma unroll 4
  for (int s8 = 0; s8 < 64; ++s8) {
    float sv = sp[s8];
    f32x4 v = *(const f32x4*)(ep + (size_t)(sc * 64 + s8) * M_);
    acc += v * sv;
  }
  *(f32x4*)(cpart + (size_t)sc * (B_ * M_) + b * M_ + m) = acc;
}

__global__ void k_ctxred(const float* __restrict__ cpart, float* __restrict__ ctx) {
  int i0 = (blockIdx.x * 256 + threadIdx.x) * 4;
  f32x4 a = {0.f, 0.f, 0.f, 0.f};
#pragma unroll
  for (int p = 0; p < 8; ++p) a += *(const f32x4*)(cpart + (size_t)p * (B_ * M_) + i0);
  *(f32x4*)(ctx + i0) = a;
}

// ---------------- GRU GEMMs: 64x64 tile, 4x4/thread, K-split x2 -------------
__global__ __launch_bounds__(256) void k_grugemm(const float* __restrict__ ctx,
                                                 const float* __restrict__ wv,
                                                 const float* __restrict__ hidden,
                                                 const float* __restrict__ Wih,
                                                 const float* __restrict__ bih,
                                                 const float* __restrict__ Whh,
                                                 const float* __restrict__ bhh,
                                                 float* __restrict__ gi0,
                                                 float* __restrict__ gi1,
                                                 float* __restrict__ gh0,
                                                 float* __restrict__ gh1) {
  __shared__ float xs[64][36];
  __shared__ float Ws[64][36];
  const int t = threadIdx.x;
  const int blk = blockIdx.x;
  const bool ghh = blk >= 96;
  const int sub = ghh ? blk - 96 : blk;
  const int colt = sub % 48, half = sub / 48;
  const int gbase = colt * 64;
  const int K = ghh ? H_ : XIN_;
  const int klo = ghh ? (half ? 512 : 0) : (half ? 1280 : 0);
  const int khi = ghh ? (half ? 1024 : 512) : (half ? 2560 : 1280);
  const float* Wp = ghh ? Whh : Wih;
  const int vb = t & 15, bb = t >> 4;
  const int srow = t >> 2, sc0 = (t & 3) * 8;
  float acc[4][4] = {};
  for (int kc = klo; kc < khi; kc += 32) {
    f32x4 xa, xb;
    if (ghh) {
      xa = *(const f32x4*)(hidden + (size_t)srow * H_ + kc + sc0);
      xb = *(const f32x4*)(hidden + (size_t)srow * H_ + kc + sc0 + 4);
    } else if (kc + sc0 < M_) {
      xa = *(const f32x4*)(ctx + (size_t)srow * M_ + kc + sc0);
      xb = *(const f32x4*)(ctx + (size_t)srow * M_ + kc + sc0 + 4);
    } else {
      xa = *(const f32x4*)(wv + (size_t)srow * E_ + kc + sc0 - M_);
      xb = *(const f32x4*)(wv + (size_t)srow * E_ + kc + sc0 - M_ + 4);
    }
    *(f32x4*)&xs[srow][sc0] = xa;
    *(f32x4*)&xs[srow][sc0 + 4] = xb;
    *(f32x4*)&Ws[srow][sc0]     = *(const f32x4*)(Wp + (size_t)(gbase + srow) * K + kc + sc0);
    *(f32x4*)&Ws[srow][sc0 + 4] = *(const f32x4*)(Wp + (size_t)(gbase + srow) * K + kc + sc0 + 4);
    __syncthreads();
#pragma unroll
    for (int kk = 0; kk < 32; ++kk) {
      float a[4], w4[4];
#pragma unroll
      for (int i = 0; i < 4; ++i) a[i] = xs[bb * 4 + i][kk];
#pragma unroll
      for (int j = 0; j < 4; ++j) w4[j] = Ws[vb + 16 * j][kk];
#pragma unroll
      for (int i = 0; i < 4; ++i)
#pragma unroll
        for (int j = 0; j < 4; ++j) acc[i][j] += a[i] * w4[j];
    }
    __syncthreads();
  }
  float* dst = ghh ? (half ? gh1 : gh0) : (half ? gi1 : gi0);
  const float* bias = ghh ? bhh : bih;
#pragma unroll
  for (int i = 0; i < 4; ++i)
#pragma unroll
    for (int j = 0; j < 4; ++j) {
      int g = gbase + vb + 16 * j;
      float v = acc[i][j] + (half ? 0.f : bias[g]);
      dst[(size_t)(bb * 4 + i) * G3_ + g] = v;
    }
}

// ---------------- GRU gates -> new_hidden (f32 + bf16 copy) ----------------
__global__ void k_gate(const float* __restrict__ gi0, const float* __restrict__ gi1,
                       const float* __restrict__ gh0, const float* __restrict__ gh1,
                       const float* __restrict__ hidden, float* __restrict__ newh,
                       unsigned short* __restrict__ newhbf) {
  int o = blockIdx.x * 256 + threadIdx.x;
  int b = o >> 10, h = o & 1023;
  size_t base = (size_t)b * G3_;
  float ir = gi0[base + h] + gi1[base + h];
  float iz = gi0[base + 1024 + h] + gi1[base + 1024 + h];
  float in = gi0[base + 2048 + h] + gi1[base + 2048 + h];
  float hr = gh0[base + h] + gh1[base + h];
  float hz = gh0[base + 1024 + h] + gh1[base + 1024 + h];
  float hn = gh0[base + 2048 + h] + gh1[base + 2048 + h];
  float r = 1.f / (1.f + expf(-(ir + hr)));
  float z = 1.f / (1.f + expf(-(iz + hz)));
  float n = tanhf(in + r * hn);
  float nh = (1.f - z) * n + z * hidden[o];
  newh[o] = nh;
  newhbf[o] = f2bf(nh);
}

// ---------------- output projection: bf16 MFMA, 64x128 tile ----------------
__global__ __launch_bounds__(256) void k_outproj_mfma(const unsigned short* __restrict__ newhbf,
                                                      const float* __restrict__ ow,
                                                      const float* __restrict__ ob,
                                                      float* __restrict__ pred) {
  __shared__ unsigned short As[2048];   // 4 KB
  __shared__ unsigned short Bs[4096];   // 8 KB
  const int t = threadIdx.x;
  const int w = t >> 6, l = t & 63;
  const int l15 = l & 15, l4 = l >> 4;
  const int vbase = blockIdx.x * 128;   // 250 blocks

  const unsigned short* aSrc = newhbf + (size_t)(t & 63) * H_ + (t >> 6) * 8;
  const int br = t >> 1, bh = t & 1;
  const float* bSrc = ow + (size_t)(vbase + br) * H_ + bh * 16;

  f32x4 acc[4][2] = {};

  for (int kc = 0; kc < H_; kc += 32) {
    async16(aSrc + kc, (char*)As + (size_t)t * 16);
    f32x4 v0 = *(const f32x4*)(bSrc + kc);
    f32x4 v1 = *(const f32x4*)(bSrc + kc + 4);
    f32x4 v2 = *(const f32x4*)(bSrc + kc + 8);
    f32x4 v3 = *(const f32x4*)(bSrc + kc + 12);
    ushort4 p0 = { f2bf(v0.x), f2bf(v0.y), f2bf(v0.z), f2bf(v0.w) };
    ushort4 p1 = { f2bf(v1.x), f2bf(v1.y), f2bf(v1.z), f2bf(v1.w) };
    ushort4 p2 = { f2bf(v2.x), f2bf(v2.y), f2bf(v2.z), f2bf(v2.w) };
    ushort4 p3 = { f2bf(v3.x), f2bf(v3.y), f2bf(v3.z), f2bf(v3.w) };
    const int kg0 = bh * 2;
    *(ushort4*)(Bs + kg0 * 1024 + br * 8)       = p0;
    *(ushort4*)(Bs + kg0 * 1024 + br * 8 + 4)   = p1;
    *(ushort4*)(Bs + (kg0 + 1) * 1024 + br * 8)     = p2;
    *(ushort4*)(Bs + (kg0 + 1) * 1024 + br * 8 + 4) = p3;
    __syncthreads();
    short8 af[4], bf[2];
#pragma unroll
    for (int rf = 0; rf < 4; ++rf)
      af[rf] = *(const short8*)(As + l4 * 512 + (rf * 16 + l15) * 8);
#pragma unroll
    for (int cf = 0; cf < 2; ++cf)
      bf[cf] = *(const short8*)(Bs + l4 * 1024 + (w * 32 + cf * 16 + l15) * 8);
#pragma unroll
    for (int rf = 0; rf < 4; ++rf)
#pragma unroll
      for (int cf = 0; cf < 2; ++cf)
        acc[rf][cf] = __builtin_amdgcn_mfma_f32_16x16x32_bf16(af[rf], bf[cf], acc[rf][cf], 0, 0, 0);
    __syncthreads();
  }

#pragma unroll
  for (int cf = 0; cf < 2; ++cf) {
    int col = vbase + w * 32 + cf * 16 + l15;
    float bias = ob[col];
#pragma unroll
    for (int rf = 0; rf < 4; ++rf)
#pragma unroll
      for (int j = 0; j < 4; ++j) {
        int row = rf * 16 + l4 * 4 + j;
        pred[(size_t)row * V_ + col] = acc[rf][cf][j] + bias;
      }
  }
}

extern "C" void kernel_launch(void* const* d_in, const int* in_sizes, int n_in,
                              void* d_out, int out_size, void* d_ws, size_t ws_size,
                              hipStream_t stream) {
  const int*   word   = (const int*)d_in[0];
  const float* hidden = (const float*)d_in[1];
  const float* enc    = (const float*)d_in[2];
  const float* emb    = (const float*)d_in[5];
  const float* lin1w  = (const float*)d_in[6];
  const float* lin1b  = (const float*)d_in[7];
  const float* lin2w  = (const float*)d_in[8];
  const float* lin2b  = (const float*)d_in[9];
  const float* vw     = (const float*)d_in[10];
  const float* Wih    = (const float*)d_in[12];
  const float* bih    = (const float*)d_in[13];
  const float* Whh    = (const float*)d_in[14];
  const float* bhh    = (const float*)d_in[15];
  const float* ow     = (const float*)d_in[16];
  const float* ob     = (const float*)d_in[17];

  float* out   = (float*)d_out;
  float* pred  = out;                   // [64][32000]
  float* newh  = out + 2048000;         // [64][1024]
  float* score = out + 2113536;         // [64][512]

  const size_t ENCBF = 134217728;       // 32768*2048*2
  const bool fast = ws_size >= ENCBF + 13107200;
  char* ws = (char*)d_ws;
  unsigned short* encbf = (unsigned short*)ws;      // fast path only
  size_t base = fast ? ENCBF : 0;
  unsigned short* bw = (unsigned short*)(ws + base);        // 4,194,304
  float* hx    = (float*)(ws + base + 4194304);             // 262,144
  float* wvbuf = (float*)(ws + base + 4456448);             // 131,072
  float* epart = (float*)(ws + base + 4587520);             // 2,097,152
  float* cpart = (float*)(ws + base + 6684672);             // 4,194,304
  float* ctx   = (float*)(ws + base + 10878976);            // 524,288
  float* gi0   = (float*)(ws + base + 11403264);            // 786,432
  float* gh0   = (float*)(ws + base + 12189696);            // 786,432
  unsigned short* nhbf = (unsigned short*)(ws + base + 12976128);  // 131,072
  // gi1/gh1 reuse the dead epart region (consumed by k_softmax first)
  float* gi1   = epart;                                     // 786,432
  float* gh1   = epart + 196608;                            // 786,432

  bool use3 = false, use2 = false;
  if (fast) {
    use3 = (hipFuncSetAttribute((const void*)k_attn3,
        hipFuncAttributeMaxDynamicSharedMemorySize, 98304) == hipSuccess);
    if (!use3)
      use2 = (hipFuncSetAttribute((const void*)k_attn2,
          hipFuncAttributeMaxDynamicSharedMemorySize, 73728) == hipSuccess);
  }

  if (fast) {
    k_convhx<<<4112, 256, 0, stream>>>(enc, encbf, lin2w, bw, word, emb, wvbuf,
                                       hidden, lin1w, lin1b, lin2b, hx);
    int npart;
    if (use3) {
      k_attn3<<<512, 512, 98304, stream>>>(encbf, bw, hx, vw, epart);
      npart = 8;
    } else if (use2) {
      k_attn2<<<1024, 512, 73728, stream>>>(encbf, bw, hx, vw, epart);
      npart = 16;
    } else {
      k_attn<<<2048, 256, 0, stream>>>((const float*)d_in[2], bw, hx, vw, epart);
      npart = 16;
    }
    k_softmax<<<64, 256, 0, stream>>>(epart, score, npart);
    k_ctxb<<<512, 256, 0, stream>>>(encbf, score, cpart);
  } else {
    k_convhx<<<4112, 256, 0, stream>>>(enc, encbf, lin2w, bw, word, emb, wvbuf,
                                       hidden, lin1w, lin1b, lin2b, hx);  // enc part unused
    k_attn<<<2048, 256, 0, stream>>>(enc, bw, hx, vw, epart);
    k_softmax<<<64, 256, 0, stream>>>(epart, score, 16);
    k_ctx<<<1024, 256, 0, stream>>>(enc, score, cpart);
  }
  k_ctxred<<<128, 256, 0, stream>>>(cpart, ctx);
  k_grugemm<<<192, 256, 0, stream>>>(ctx, wvbuf, hidden, Wih, bih, Whh, bhh, gi0, gi1, gh0, gh1);
  k_gate<<<256, 256, 0, stream>>>(gi0, gi1, gh0, gh1, hidden, newh, nhbf);
  k_outproj_mfma<<<250, 256, 0, stream>>>(nhbf, ow, ob, pred);
}